// Round 2
// baseline (654.539 us; speedup 1.0000x reference)
//
#include <hip/hip_runtime.h>
#include <hip/hip_bf16.h>

// MHA forward, round 8: spill-free attn_mean via gld16 staging + 64x64 tiles.
// Round-7 attn_mean_k spilled (~229 MB scratch writes, VGPR=64 < ~88 live).
// New attn_mean_k: 64q x 64k per block, global_load_lds staging with
// pre-swizzled global source (inverse of tile_off), no ds_writes, macc=16.
// S=2048 B=2 E=1024 H=16 D=64. scale folded into Q (exp2).
// ws (48.3 MB): xb | qwb | owb | Qp | Kp | Vt | wab | rl | flag
// d_out: out[S,B,E] fp32 (4194304) then attn_mean[B,S,S] fp32 (8388608).

#define Sq 2048
#define Bb 2
#define Ee 1024
#define Hh 16
#define Dd 64
#define LOG2E 1.4426950408889634f
#define QSCALE 0.18033688011112042f   // 0.125 * log2(e)

typedef __attribute__((ext_vector_type(8))) short bhalf8;   // 8 bf16 (4 VGPRs)
typedef __attribute__((ext_vector_type(4))) float f32x4;

__device__ __forceinline__ void gld16(const __hip_bfloat16* g, __hip_bfloat16* l) {
    __builtin_amdgcn_global_load_lds(
        (const __attribute__((address_space(1))) unsigned int*)g,
        (__attribute__((address_space(3))) unsigned int*)l, 16, 0, 0);
}

__device__ __forceinline__ int pkbf(float a, float b) {
    union { __hip_bfloat16 h[2]; int i; } u;
    u.h[0] = __float2bfloat16(a);
    u.h[1] = __float2bfloat16(b);
    return u.i;
}

// slot s (0..511, 16B chunks of a 64x64 bf16 tile, global-linear) -> swizzled
// frag-major LDS elem offset [f|ks][j|nd][quad][lm][8]
__device__ __forceinline__ int tile_off(int s) {
    return ((s >> 2) & 1) * 2048 + (s >> 7) * 512 + (s & 3) * 128 + ((s >> 3) & 15) * 8;
}

// K row permutation: LDS tile row position p holds global key kperm(p).
// p = j*16 + quad*4 + r  ->  key = 32*(j&1) + 8*quad + 4*(j>>1) + r
// so that the QK^T C-registers directly form the PV B-fragment (no shuffles).
__device__ __forceinline__ int kperm(int p) {
    return (p & 3) | (((p >> 5) & 1) << 2) | ((p & 12) << 1) | (((p >> 4) & 1) << 5);
}

// ---------------- fused prep: mask scan + fp32->bf16 conversions ----------------
__global__ __launch_bounds__(256) void prep_k(
    const float* __restrict__ x, const float* __restrict__ am,
    const unsigned int* __restrict__ kpm32,
    const float* __restrict__ qkv_w, const float* __restrict__ out_w,
    __hip_bfloat16* __restrict__ xb, __hip_bfloat16* __restrict__ qwb,
    __hip_bfloat16* __restrict__ owb, unsigned int* __restrict__ flag)
{
    const long i = (long)blockIdx.x*256 + threadIdx.x;
    if (i < 1048576) {                       // mask scan (am 1M float4, kpm 1024 u32)
        float4 v = ((const float4*)am)[i];
        bool nz = (v.x != 0.f) | (v.y != 0.f) | (v.z != 0.f) | (v.w != 0.f);
        if (i < 1024) nz |= (kpm32[i] != 0u);
        if (__ballot(nz)) { if ((threadIdx.x & 63) == 0) atomicOr(flag, 1u); }
    } else if (i < 2097152) {                // x conv with [S,B,E]->[B*S][E]
        const long j = i - 1048576;
        const int m = (int)(j >> 8), e4 = (int)(j & 255);
        const int b = m >> 11, s = m & 2047;
        float4 v = ((const float4*)x)[(size_t)(s*Bb + b)*256 + e4];
        union { __hip_bfloat16 h[4]; uint2 u; } o;
        o.h[0]=__float2bfloat16(v.x); o.h[1]=__float2bfloat16(v.y);
        o.h[2]=__float2bfloat16(v.z); o.h[3]=__float2bfloat16(v.w);
        ((uint2*)xb)[(size_t)m*256 + e4] = o.u;
    } else if (i < 2883584) {                // qkv_w conv (786432 float4)
        const long j = i - 2097152;
        float4 v = ((const float4*)qkv_w)[j];
        union { __hip_bfloat16 h[4]; uint2 u; } o;
        o.h[0]=__float2bfloat16(v.x); o.h[1]=__float2bfloat16(v.y);
        o.h[2]=__float2bfloat16(v.z); o.h[3]=__float2bfloat16(v.w);
        ((uint2*)qwb)[j] = o.u;
    } else if (i < 3145728) {                // out_w conv (262144 float4)
        const long j = i - 2883584;
        float4 v = ((const float4*)out_w)[j];
        union { __hip_bfloat16 h[4]; uint2 u; } o;
        o.h[0]=__float2bfloat16(v.x); o.h[1]=__float2bfloat16(v.y);
        o.h[2]=__float2bfloat16(v.z); o.h[3]=__float2bfloat16(v.w);
        ((uint2*)owb)[j] = o.u;
    }
}

// ---------------- GEMM 1: QKV projection, bf16 MFMA, scatter epilogue ----------------
// Q stored pre-scaled by QSCALE.
__global__ __launch_bounds__(256) void gemm_qkv(
    const __hip_bfloat16* __restrict__ A, const __hip_bfloat16* __restrict__ Bw,
    const float* __restrict__ bias,
    __hip_bfloat16* __restrict__ Qp, __hip_bfloat16* __restrict__ Kp,
    __hip_bfloat16* __restrict__ Vt)
{
    __shared__ __align__(16) __hip_bfloat16 As[128*32];
    __shared__ __align__(16) __hip_bfloat16 Bs[128*32];
    const int t = threadIdx.x;
    const int l = t & 63, lm = l & 15, quad = l >> 4;
    const int w = t >> 6;
    const int mw = (w & 1)*64, nw = (w >> 1)*64;
    const int m0 = blockIdx.y*128, n0 = blockIdx.x*128;

    const int srow = t >> 2;              // 0..63
    const int scol = (t & 3)*8;
    const __hip_bfloat16* ag = A  + (size_t)(m0 + srow)*1024 + scol;
    const __hip_bfloat16* bg = Bw + (size_t)(n0 + srow)*1024 + scol;
    __hip_bfloat16* al = As + t*8;
    __hip_bfloat16* bl = Bs + t*8;

    f32x4 acc[4][4] = {};
    for (int k0 = 0; k0 < 1024; k0 += 32) {
        __syncthreads();
        gld16(ag + k0, al);
        gld16(ag + (size_t)64*1024 + k0, al + 2048);
        gld16(bg + k0, bl);
        gld16(bg + (size_t)64*1024 + k0, bl + 2048);
        __syncthreads();
        bhalf8 af[4], bf[4];
#pragma unroll
        for (int i = 0; i < 4; i++) {
            af[i] = *(const bhalf8*)&As[(mw + i*16 + lm)*32 + quad*8];
            bf[i] = *(const bhalf8*)&Bs[(nw + i*16 + lm)*32 + quad*8];
        }
#pragma unroll
        for (int mf = 0; mf < 4; mf++)
#pragma unroll
            for (int nf = 0; nf < 4; nf++)
                acc[mf][nf] = __builtin_amdgcn_mfma_f32_16x16x32_bf16(af[mf], bf[nf], acc[mf][nf], 0,0,0);
    }
#pragma unroll
    for (int nf = 0; nf < 4; nf++) {
        const int n = n0 + nw + nf*16 + lm;
        const float bz = bias[n];
        const int which = n >> 10, hh = (n >> 6) & 15, dd = n & 63;
#pragma unroll
        for (int mf = 0; mf < 4; mf++)
#pragma unroll
            for (int r = 0; r < 4; r++) {
                const int m = m0 + mw + mf*16 + quad*4 + r;
                const int b2 = m >> 11, s2 = m & 2047;
                const float vf = acc[mf][nf][r] + bz;
                if (which == 0)
                    Qp[((size_t)(b2*Hh + hh)*Sq + s2)*Dd + dd] = __float2bfloat16(vf * QSCALE);
                else if (which == 1)
                    Kp[((size_t)(b2*Hh + hh)*Sq + s2)*Dd + dd] = __float2bfloat16(vf);
                else
                    Vt[((size_t)(b2*Hh + hh)*Dd + dd)*Sq + s2] = __float2bfloat16(vf);
            }
    }
}

// ---------------- Attention core: LDS-staged tiles, XCD-pinned, shuffle-free PV ----------------
// blk = xcd + 8*qt + 256*grp ; bh = grp*8 + xcd. Block = 4 waves x 16 q rows.
// Per kt: K tile (8KB) + V^T tile (8KB) staged into swizzled frag-major LDS.
// K rows are permuted at the GLOBAL source (kperm) so that the QK^T output
// registers directly form the PV B-fragment: no ds_bpermute in the PV step.
__global__ __launch_bounds__(256, 4) void attn_mfma(
    const __hip_bfloat16* __restrict__ Qp, const __hip_bfloat16* __restrict__ Kp,
    const __hip_bfloat16* __restrict__ Vt,
    const float* __restrict__ am, const unsigned char* __restrict__ kpm,
    const unsigned int* __restrict__ flag,
    __hip_bfloat16* __restrict__ wa, float* __restrict__ rlbuf)
{
    __shared__ __align__(16) __hip_bfloat16 Ks[4096];
    __shared__ __align__(16) __hip_bfloat16 Vs[4096];
    const int t = threadIdx.x;
    const int w = t >> 6, l = t & 63, lm = l & 15, quad = l >> 4;
    const int blk = blockIdx.x;
    const int xcd = blk & 7;
    const int qt  = (blk >> 3) & 31;
    const int grp = blk >> 8;                  // 0..3
    const int bh  = grp*8 + xcd;
    const int b   = bh >> 4, h = bh & 15;
    const int q   = qt*64 + w*16 + lm;
    const bool masked = (flag[0] != 0u);

    const __hip_bfloat16* qbase = Qp + (size_t)bh*Sq*Dd;
    const __hip_bfloat16* kbase = Kp + (size_t)bh*Sq*Dd;
    const __hip_bfloat16* vbase = Vt + (size_t)bh*Dd*Sq;

    // Q as B-operand (pre-scaled), one-time strided load
    bhalf8 bq[2];
    bq[0] = *(const bhalf8*)(qbase + (size_t)q*Dd + quad*8);
    bq[1] = *(const bhalf8*)(qbase + (size_t)q*Dd + quad*8 + 32);

    f32x4 o[4] = {};
    float lsum = 0.f;

    // LDS write offsets for this thread's two slots (linear, conflict-free)
    const int off0 = tile_off(t), off1 = tile_off(t + 256);
    // permuted global K rows feeding those slots
    const int krow0 = kperm(t >> 3);
    const int krow1 = kperm(32 + (t >> 3));
    const int kcol  = (t & 7)*8;

    // preload tile 0 staging regs
    uint4 kreg0 = *(const uint4*)(kbase + (size_t)krow0*Dd + kcol);
    uint4 kreg1 = *(const uint4*)(kbase + (size_t)krow1*Dd + kcol);
    uint4 vreg0 = *(const uint4*)(vbase + (size_t)(t >> 3)*Sq + (t & 7)*8);
    uint4 vreg1 = *(const uint4*)(vbase + (size_t)((t + 256) >> 3)*Sq + (t & 7)*8);

    for (int kt = 0; kt < 32; kt++) {
        __syncthreads();                       // previous tile's readers done
        *(uint4*)&Ks[off0] = kreg0;
        *(uint4*)&Ks[off1] = kreg1;
        *(uint4*)&Vs[off0] = vreg0;
        *(uint4*)&Vs[off1] = vreg1;
        if (kt < 31) {                         // prefetch tile kt+1
            const int kn = (kt + 1)*64;
            kreg0 = *(const uint4*)(kbase + (size_t)(kn + krow0)*Dd + kcol);
            kreg1 = *(const uint4*)(kbase + (size_t)(kn + krow1)*Dd + kcol);
            vreg0 = *(const uint4*)(vbase + (size_t)(t >> 3)*Sq + kn + (t & 7)*8);
            vreg1 = *(const uint4*)(vbase + (size_t)((t + 256) >> 3)*Sq + kn + (t & 7)*8);
        }
        __syncthreads();                       // tile kt visible

        const int k0 = kt*64;
        // S^T = K · Q^T  (K rows permuted: row p holds key kperm(p))
        f32x4 s[4] = {};
#pragma unroll
        for (int f = 0; f < 2; f++) {
            bhalf8 ak[4];
#pragma unroll
            for (int j = 0; j < 4; j++)
                ak[j] = *(const bhalf8*)&Ks[f*2048 + j*512 + l*8];
#pragma unroll
            for (int j = 0; j < 4; j++)
                s[j] = __builtin_amdgcn_mfma_f32_16x16x32_bf16(ak[j], bq[f], s[j], 0,0,0);
        }

        // exp2 + pack; s[j][r] is key k0 + 32*(j&1) + 8*quad + 4*(j>>1) + r
        int pk[4][2];
#pragma unroll
        for (int j = 0; j < 4; j++) {
            float p[4];
#pragma unroll
            for (int r = 0; r < 4; r++) {
                float sv = s[j][r];
                if (masked) {
                    const int key = k0 + 32*(j & 1) + 8*quad + 4*(j >> 1) + r;
                    const float km = kpm[b*Sq + key] ? -1e30f : 0.0f;
                    sv += (am[(size_t)q*Sq + key] + km) * LOG2E;
                }
                p[r] = exp2f(sv);
            }
            lsum += (p[0]+p[1]) + (p[2]+p[3]);
            pk[j][0] = pkbf(p[0], p[1]);
            pk[j][1] = pkbf(p[2], p[3]);
        }

        // PV: O^T += V^T · P^T — P^T B-frag is lane-local by construction:
        // lane needs keys ks*32 + quad*8 + e  ==  {pk[ks], pk[ks+2]}
#pragma unroll
        for (int ks = 0; ks < 2; ks++) {
            union { int i[4]; bhalf8 v; } bp;
            bp.i[0] = pk[ks][0];
            bp.i[1] = pk[ks][1];
            bp.i[2] = pk[ks + 2][0];
            bp.i[3] = pk[ks + 2][1];
            bhalf8 av[4];
#pragma unroll
            for (int nd = 0; nd < 4; nd++)
                av[nd] = *(const bhalf8*)&Vs[ks*2048 + nd*512 + l*8];
#pragma unroll
            for (int nd = 0; nd < 4; nd++)
                o[nd] = __builtin_amdgcn_mfma_f32_16x16x32_bf16(av[nd], bp.v, o[nd], 0,0,0);
        }
    }

    lsum += __shfl_xor(lsum, 16, 64);
    lsum += __shfl_xor(lsum, 32, 64);
    const float rl = 1.0f / lsum;
    if (quad == 0) rlbuf[(size_t)bh*Sq + q] = rl;

#pragma unroll
    for (int nd = 0; nd < 4; nd++) {
        union { __hip_bfloat16 hx[4]; uint2 u; } ou;
#pragma unroll
        for (int r = 0; r < 4; r++) ou.hx[r] = __float2bfloat16(o[nd][r] * rl);
        *(uint2*)(wa + ((size_t)b*Sq + q)*Ee + h*Dd + nd*16 + quad*4) = ou.u;
    }
}

// ---------------- attn_mean: 64q x 64k per block, gld16 staging, no spills ----------------
// Wave w owns q rows [q0 + w*16, +16). K and Q tiles (8KB each) staged via
// global_load_lds with pre-swizzled global source (inverse of tile_off):
// wave w call c lane l fills LDS slot u = w*128 + c*64 + l from global slot
// s = ((w&1)*2+c)<<7 | (l&15)<<3 | (w>>1)<<2 | (l>>4).
__global__ __launch_bounds__(256, 4) void attn_mean_k(
    const __hip_bfloat16* __restrict__ Qp, const __hip_bfloat16* __restrict__ Kp,
    const float* __restrict__ am, const unsigned char* __restrict__ kpm,
    const unsigned int* __restrict__ flag,
    const float* __restrict__ rlbuf, float* __restrict__ attn_mean)
{
    __shared__ __align__(16) __hip_bfloat16 Ks[4096];   // 64 keys x 64 d, frag-major
    __shared__ __align__(16) __hip_bfloat16 Qs[4096];   // 64 q    x 64 d, frag-major
    const int t = threadIdx.x;
    const int w = t >> 6, l = t & 63, lm = l & 15, quad = l >> 4;
    const int b  = blockIdx.z;
    const int q0 = blockIdx.y * 64;
    const int kc = blockIdx.x * 64;
    const bool masked = (flag[0] != 0u);

    // pre-swizzled global source slot (c=0); c=1 adds 128 slots (1024 elems)
    const int s0 = ((w & 1) << 8) | (lm << 3) | ((w >> 1) << 2) | (l >> 4);
    __hip_bfloat16* kl = Ks + w*1024;
    __hip_bfloat16* ql = Qs + w*1024;

    float macc[4][4] = {};
    const float* rlp = rlbuf + (size_t)(b*Hh)*Sq + q0 + w*16 + quad*4;

    for (int h = 0; h < Hh; h++) {
        const __hip_bfloat16* kg = Kp + ((size_t)(b*Hh + h)*Sq + kc)*Dd + s0*8;
        const __hip_bfloat16* qg = Qp + ((size_t)(b*Hh + h)*Sq + q0)*Dd + s0*8;
        __syncthreads();                      // previous iteration's readers done
        gld16(kg, kl);       gld16(kg + 1024, kl + 512);
        gld16(qg, ql);       gld16(qg + 1024, ql + 512);
        __syncthreads();                      // tiles visible (vmcnt drained)

        f32x4 s[4] = {};
#pragma unroll
        for (int f = 0; f < 2; f++) {
            bhalf8 aq = *(const bhalf8*)&Qs[f*2048 + w*512 + l*8];
#pragma unroll
            for (int j = 0; j < 4; j++) {
                bhalf8 bk = *(const bhalf8*)&Ks[f*2048 + j*512 + l*8];
                s[j] = __builtin_amdgcn_mfma_f32_16x16x32_bf16(aq, bk, s[j], 0,0,0);
            }
        }
        float rl4[4];
#pragma unroll
        for (int r = 0; r < 4; r++) rl4[r] = rlp[(size_t)h*Sq + r] * 0.0625f;
#pragma unroll
        for (int j = 0; j < 4; j++)
#pragma unroll
            for (int r = 0; r < 4; r++) {
                float sv = s[j][r];
                if (masked) {
                    const int key = kc + j*16 + lm;
                    const float km = kpm[b*Sq + key] ? -1e30f : 0.0f;
                    sv += (am[(size_t)(q0 + w*16 + quad*4 + r)*Sq + key] + km) * LOG2E;
                }
                macc[j][r] += exp2f(sv) * rl4[r];
            }
    }
#pragma unroll
    for (int j = 0; j < 4; j++)
#pragma unroll
        for (int r = 0; r < 4; r++)
            attn_mean[((size_t)b*Sq + q0 + w*16 + quad*4 + r)*Sq + kc + j*16 + lm] =
                macc[j][r];
}

// ---------------- GEMM 2: output projection, bf16 MFMA ----------------
__global__ __launch_bounds__(256) void gemm_out(
    const __hip_bfloat16* __restrict__ A, const __hip_bfloat16* __restrict__ Bw,
    const float* __restrict__ bias, float* __restrict__ outp)
{
    __shared__ __align__(16) __hip_bfloat16 As[128*32];
    __shared__ __align__(16) __hip_bfloat16 Bs[128*32];
    const int t = threadIdx.x;
    const int l = t & 63, lm = l & 15, quad = l >> 4;
    const int w = t >> 6;
    const int mw = (w & 1)*64, nw = (w >> 1)*64;
    const int m0 = blockIdx.y*128, n0 = blockIdx.x*128;

    const int srow = t >> 2;
    const int scol = (t & 3)*8;
    const __hip_bfloat16* ag = A  + (size_t)(m0 + srow)*1024 + scol;
    const __hip_bfloat16* bg = Bw + (size_t)(n0 + srow)*1024 + scol;
    __hip_bfloat16* al = As + t*8;
    __hip_bfloat16* bl = Bs + t*8;

    f32x4 acc[4][4] = {};
    for (int k0 = 0; k0 < 1024; k0 += 32) {
        __syncthreads();
        gld16(ag + k0, al);
        gld16(ag + (size_t)64*1024 + k0, al + 2048);
        gld16(bg + k0, bl);
        gld16(bg + (size_t)64*1024 + k0, bl + 2048);
        __syncthreads();
        bhalf8 af[4], bf[4];
#pragma unroll
        for (int i = 0; i < 4; i++) {
            af[i] = *(const bhalf8*)&As[(mw + i*16 + lm)*32 + quad*8];
            bf[i] = *(const bhalf8*)&Bs[(nw + i*16 + lm)*32 + quad*8];
        }
#pragma unroll
        for (int mf = 0; mf < 4; mf++)
#pragma unroll
            for (int nf = 0; nf < 4; nf++)
                acc[mf][nf] = __builtin_amdgcn_mfma_f32_16x16x32_bf16(af[mf], bf[nf], acc[mf][nf], 0,0,0);
    }
#pragma unroll
    for (int nf = 0; nf < 4; nf++) {
        const int n = n0 + nw + nf*16 + lm;
        const float bz = bias[n];
#pragma unroll
        for (int mf = 0; mf < 4; mf++)
#pragma unroll
            for (int r = 0; r < 4; r++) {
                const int m = m0 + mw + mf*16 + quad*4 + r;
                const int b2 = m >> 11, s2 = m & 2047;
                outp[((size_t)s2*Bb + b2)*Ee + n] = acc[mf][nf][r] + bz;
            }
    }
}

extern "C" void kernel_launch(void* const* d_in, const int* in_sizes, int n_in,
                              void* d_out, int out_size, void* d_ws, size_t ws_size,
                              hipStream_t stream) {
    const float*         x         = (const float*)d_in[0];
    const float*         attn_mask = (const float*)d_in[1];
    const unsigned char* kpm       = (const unsigned char*)d_in[2];
    const float*         qkv_w     = (const float*)d_in[3];
    const float*         qkv_b     = (const float*)d_in[4];
    const float*         out_w     = (const float*)d_in[5];
    const float*         out_b     = (const float*)d_in[6];

    float* outp      = (float*)d_out;
    float* attn_mean = outp + 4194304;          // S*B*E

    __hip_bfloat16* xb  = (__hip_bfloat16*)d_ws;     // 8 MB
    __hip_bfloat16* qwb = xb  + 4194304;             // 6 MB
    __hip_bfloat16* owb = qwb + 3145728;             // 2 MB
    __hip_bfloat16* Qp  = owb + 1048576;             // 8 MB (pre-scaled by QSCALE)
    __hip_bfloat16* Kp  = Qp  + 4194304;             // 8 MB
    __hip_bfloat16* Vt  = Kp  + 4194304;             // 8 MB (transposed [B,H,D,S])
    __hip_bfloat16* wab = Vt  + 4194304;             // 8 MB
    float* rlbuf        = (float*)(wab + 4194304);   // 256 KB
    unsigned int* flag  = (unsigned int*)(rlbuf + 65536);

    hipMemsetAsync(flag, 0, sizeof(unsigned int), stream);
    prep_k<<<12288, 256, 0, stream>>>(x, attn_mask, (const unsigned int*)kpm,
                                      qkv_w, out_w, xb, qwb, owb, flag);
    gemm_qkv<<<dim3(24, 32), 256, 0, stream>>>(xb, qwb, qkv_b, Qp, Kp, Vt);
    attn_mfma<<<dim3(1024), 256, 0, stream>>>(Qp, Kp, Vt, attn_mask, kpm, flag, wab, rlbuf);
    attn_mean_k<<<dim3(32, 32, Bb), 256, 0, stream>>>(Qp, Kp, attn_mask, kpm, flag, rlbuf, attn_mean);
    gemm_out<<<dim3(8, 32), 256, 0, stream>>>(wab, owb, out_b, outp);
}

// Round 3
// 646.244 us; speedup vs baseline: 1.0128x; 1.0128x over previous
//
#include <hip/hip_runtime.h>
#include <hip/hip_bf16.h>

// MHA forward, round 9: attn_mean with contiguous reg-staged K + direct-global Q.
// Round-8 post-mortem: gld16 with tile_off-scattered source destroyed L2 reuse
// (FETCH 498MB = full demand) -> traffic-bound 390us. Round 9: K tile staged
// via CONTIGUOUS uint4 reads + ds_write to frag-major layout (round-7-proven
// 57MB FETCH); Q fragments read directly from global (each wave owns its own
// 16 q rows; no LDS, no barrier); 64q x 64k tile keeps live regs ~60 (no spill,
// which was round-7's 222MB excess write).
// S=2048 B=2 E=1024 H=16 D=64. scale folded into Q (exp2).
// ws (48.3 MB): xb | qwb | owb | Qp | Kp | Vt | wab | rl | flag
// d_out: out[S,B,E] fp32 (4194304) then attn_mean[B,S,S] fp32 (8388608).

#define Sq 2048
#define Bb 2
#define Ee 1024
#define Hh 16
#define Dd 64
#define LOG2E 1.4426950408889634f
#define QSCALE 0.18033688011112042f   // 0.125 * log2(e)

typedef __attribute__((ext_vector_type(8))) short bhalf8;   // 8 bf16 (4 VGPRs)
typedef __attribute__((ext_vector_type(4))) float f32x4;

__device__ __forceinline__ void gld16(const __hip_bfloat16* g, __hip_bfloat16* l) {
    __builtin_amdgcn_global_load_lds(
        (const __attribute__((address_space(1))) unsigned int*)g,
        (__attribute__((address_space(3))) unsigned int*)l, 16, 0, 0);
}

__device__ __forceinline__ int pkbf(float a, float b) {
    union { __hip_bfloat16 h[2]; int i; } u;
    u.h[0] = __float2bfloat16(a);
    u.h[1] = __float2bfloat16(b);
    return u.i;
}

// slot s (0..511, 16B chunks of a 64x64 bf16 tile, global-linear) -> swizzled
// frag-major LDS elem offset [f|ks][j|nd][quad][lm][8]
__device__ __forceinline__ int tile_off(int s) {
    return ((s >> 2) & 1) * 2048 + (s >> 7) * 512 + (s & 3) * 128 + ((s >> 3) & 15) * 8;
}

// K row permutation: LDS tile row position p holds global key kperm(p).
// p = j*16 + quad*4 + r  ->  key = 32*(j&1) + 8*quad + 4*(j>>1) + r
// so that the QK^T C-registers directly form the PV B-fragment (no shuffles).
__device__ __forceinline__ int kperm(int p) {
    return (p & 3) | (((p >> 5) & 1) << 2) | ((p & 12) << 1) | (((p >> 4) & 1) << 5);
}

// ---------------- fused prep: mask scan + fp32->bf16 conversions ----------------
__global__ __launch_bounds__(256) void prep_k(
    const float* __restrict__ x, const float* __restrict__ am,
    const unsigned int* __restrict__ kpm32,
    const float* __restrict__ qkv_w, const float* __restrict__ out_w,
    __hip_bfloat16* __restrict__ xb, __hip_bfloat16* __restrict__ qwb,
    __hip_bfloat16* __restrict__ owb, unsigned int* __restrict__ flag)
{
    const long i = (long)blockIdx.x*256 + threadIdx.x;
    if (i < 1048576) {                       // mask scan (am 1M float4, kpm 1024 u32)
        float4 v = ((const float4*)am)[i];
        bool nz = (v.x != 0.f) | (v.y != 0.f) | (v.z != 0.f) | (v.w != 0.f);
        if (i < 1024) nz |= (kpm32[i] != 0u);
        if (__ballot(nz)) { if ((threadIdx.x & 63) == 0) atomicOr(flag, 1u); }
    } else if (i < 2097152) {                // x conv with [S,B,E]->[B*S][E]
        const long j = i - 1048576;
        const int m = (int)(j >> 8), e4 = (int)(j & 255);
        const int b = m >> 11, s = m & 2047;
        float4 v = ((const float4*)x)[(size_t)(s*Bb + b)*256 + e4];
        union { __hip_bfloat16 h[4]; uint2 u; } o;
        o.h[0]=__float2bfloat16(v.x); o.h[1]=__float2bfloat16(v.y);
        o.h[2]=__float2bfloat16(v.z); o.h[3]=__float2bfloat16(v.w);
        ((uint2*)xb)[(size_t)m*256 + e4] = o.u;
    } else if (i < 2883584) {                // qkv_w conv (786432 float4)
        const long j = i - 2097152;
        float4 v = ((const float4*)qkv_w)[j];
        union { __hip_bfloat16 h[4]; uint2 u; } o;
        o.h[0]=__float2bfloat16(v.x); o.h[1]=__float2bfloat16(v.y);
        o.h[2]=__float2bfloat16(v.z); o.h[3]=__float2bfloat16(v.w);
        ((uint2*)qwb)[j] = o.u;
    } else if (i < 3145728) {                // out_w conv (262144 float4)
        const long j = i - 2883584;
        float4 v = ((const float4*)out_w)[j];
        union { __hip_bfloat16 h[4]; uint2 u; } o;
        o.h[0]=__float2bfloat16(v.x); o.h[1]=__float2bfloat16(v.y);
        o.h[2]=__float2bfloat16(v.z); o.h[3]=__float2bfloat16(v.w);
        ((uint2*)owb)[j] = o.u;
    }
}

// ---------------- GEMM 1: QKV projection, bf16 MFMA, scatter epilogue ----------------
// Q stored pre-scaled by QSCALE.
__global__ __launch_bounds__(256) void gemm_qkv(
    const __hip_bfloat16* __restrict__ A, const __hip_bfloat16* __restrict__ Bw,
    const float* __restrict__ bias,
    __hip_bfloat16* __restrict__ Qp, __hip_bfloat16* __restrict__ Kp,
    __hip_bfloat16* __restrict__ Vt)
{
    __shared__ __align__(16) __hip_bfloat16 As[128*32];
    __shared__ __align__(16) __hip_bfloat16 Bs[128*32];
    const int t = threadIdx.x;
    const int l = t & 63, lm = l & 15, quad = l >> 4;
    const int w = t >> 6;
    const int mw = (w & 1)*64, nw = (w >> 1)*64;
    const int m0 = blockIdx.y*128, n0 = blockIdx.x*128;

    const int srow = t >> 2;              // 0..63
    const int scol = (t & 3)*8;
    const __hip_bfloat16* ag = A  + (size_t)(m0 + srow)*1024 + scol;
    const __hip_bfloat16* bg = Bw + (size_t)(n0 + srow)*1024 + scol;
    __hip_bfloat16* al = As + t*8;
    __hip_bfloat16* bl = Bs + t*8;

    f32x4 acc[4][4] = {};
    for (int k0 = 0; k0 < 1024; k0 += 32) {
        __syncthreads();
        gld16(ag + k0, al);
        gld16(ag + (size_t)64*1024 + k0, al + 2048);
        gld16(bg + k0, bl);
        gld16(bg + (size_t)64*1024 + k0, bl + 2048);
        __syncthreads();
        bhalf8 af[4], bf[4];
#pragma unroll
        for (int i = 0; i < 4; i++) {
            af[i] = *(const bhalf8*)&As[(mw + i*16 + lm)*32 + quad*8];
            bf[i] = *(const bhalf8*)&Bs[(nw + i*16 + lm)*32 + quad*8];
        }
#pragma unroll
        for (int mf = 0; mf < 4; mf++)
#pragma unroll
            for (int nf = 0; nf < 4; nf++)
                acc[mf][nf] = __builtin_amdgcn_mfma_f32_16x16x32_bf16(af[mf], bf[nf], acc[mf][nf], 0,0,0);
    }
#pragma unroll
    for (int nf = 0; nf < 4; nf++) {
        const int n = n0 + nw + nf*16 + lm;
        const float bz = bias[n];
        const int which = n >> 10, hh = (n >> 6) & 15, dd = n & 63;
#pragma unroll
        for (int mf = 0; mf < 4; mf++)
#pragma unroll
            for (int r = 0; r < 4; r++) {
                const int m = m0 + mw + mf*16 + quad*4 + r;
                const int b2 = m >> 11, s2 = m & 2047;
                const float vf = acc[mf][nf][r] + bz;
                if (which == 0)
                    Qp[((size_t)(b2*Hh + hh)*Sq + s2)*Dd + dd] = __float2bfloat16(vf * QSCALE);
                else if (which == 1)
                    Kp[((size_t)(b2*Hh + hh)*Sq + s2)*Dd + dd] = __float2bfloat16(vf);
                else
                    Vt[((size_t)(b2*Hh + hh)*Dd + dd)*Sq + s2] = __float2bfloat16(vf);
            }
    }
}

// ---------------- Attention core: LDS-staged tiles, XCD-pinned, shuffle-free PV ----------------
// blk = xcd + 8*qt + 256*grp ; bh = grp*8 + xcd. Block = 4 waves x 16 q rows.
// Per kt: K tile (8KB) + V^T tile (8KB) staged into swizzled frag-major LDS.
// K rows are permuted at the GLOBAL source (kperm) so that the QK^T output
// registers directly form the PV B-fragment: no ds_bpermute in the PV step.
__global__ __launch_bounds__(256, 4) void attn_mfma(
    const __hip_bfloat16* __restrict__ Qp, const __hip_bfloat16* __restrict__ Kp,
    const __hip_bfloat16* __restrict__ Vt,
    const float* __restrict__ am, const unsigned char* __restrict__ kpm,
    const unsigned int* __restrict__ flag,
    __hip_bfloat16* __restrict__ wa, float* __restrict__ rlbuf)
{
    __shared__ __align__(16) __hip_bfloat16 Ks[4096];
    __shared__ __align__(16) __hip_bfloat16 Vs[4096];
    const int t = threadIdx.x;
    const int w = t >> 6, l = t & 63, lm = l & 15, quad = l >> 4;
    const int blk = blockIdx.x;
    const int xcd = blk & 7;
    const int qt  = (blk >> 3) & 31;
    const int grp = blk >> 8;                  // 0..3
    const int bh  = grp*8 + xcd;
    const int b   = bh >> 4, h = bh & 15;
    const int q   = qt*64 + w*16 + lm;
    const bool masked = (flag[0] != 0u);

    const __hip_bfloat16* qbase = Qp + (size_t)bh*Sq*Dd;
    const __hip_bfloat16* kbase = Kp + (size_t)bh*Sq*Dd;
    const __hip_bfloat16* vbase = Vt + (size_t)bh*Dd*Sq;

    // Q as B-operand (pre-scaled), one-time strided load
    bhalf8 bq[2];
    bq[0] = *(const bhalf8*)(qbase + (size_t)q*Dd + quad*8);
    bq[1] = *(const bhalf8*)(qbase + (size_t)q*Dd + quad*8 + 32);

    f32x4 o[4] = {};
    float lsum = 0.f;

    // LDS write offsets for this thread's two slots (linear, conflict-free)
    const int off0 = tile_off(t), off1 = tile_off(t + 256);
    // permuted global K rows feeding those slots
    const int krow0 = kperm(t >> 3);
    const int krow1 = kperm(32 + (t >> 3));
    const int kcol  = (t & 7)*8;

    // preload tile 0 staging regs
    uint4 kreg0 = *(const uint4*)(kbase + (size_t)krow0*Dd + kcol);
    uint4 kreg1 = *(const uint4*)(kbase + (size_t)krow1*Dd + kcol);
    uint4 vreg0 = *(const uint4*)(vbase + (size_t)(t >> 3)*Sq + (t & 7)*8);
    uint4 vreg1 = *(const uint4*)(vbase + (size_t)((t + 256) >> 3)*Sq + (t & 7)*8);

    for (int kt = 0; kt < 32; kt++) {
        __syncthreads();                       // previous tile's readers done
        *(uint4*)&Ks[off0] = kreg0;
        *(uint4*)&Ks[off1] = kreg1;
        *(uint4*)&Vs[off0] = vreg0;
        *(uint4*)&Vs[off1] = vreg1;
        if (kt < 31) {                         // prefetch tile kt+1
            const int kn = (kt + 1)*64;
            kreg0 = *(const uint4*)(kbase + (size_t)(kn + krow0)*Dd + kcol);
            kreg1 = *(const uint4*)(kbase + (size_t)(kn + krow1)*Dd + kcol);
            vreg0 = *(const uint4*)(vbase + (size_t)(t >> 3)*Sq + kn + (t & 7)*8);
            vreg1 = *(const uint4*)(vbase + (size_t)((t + 256) >> 3)*Sq + kn + (t & 7)*8);
        }
        __syncthreads();                       // tile kt visible

        const int k0 = kt*64;
        // S^T = K · Q^T  (K rows permuted: row p holds key kperm(p))
        f32x4 s[4] = {};
#pragma unroll
        for (int f = 0; f < 2; f++) {
            bhalf8 ak[4];
#pragma unroll
            for (int j = 0; j < 4; j++)
                ak[j] = *(const bhalf8*)&Ks[f*2048 + j*512 + l*8];
#pragma unroll
            for (int j = 0; j < 4; j++)
                s[j] = __builtin_amdgcn_mfma_f32_16x16x32_bf16(ak[j], bq[f], s[j], 0,0,0);
        }

        // exp2 + pack; s[j][r] is key k0 + 32*(j&1) + 8*quad + 4*(j>>1) + r
        int pk[4][2];
#pragma unroll
        for (int j = 0; j < 4; j++) {
            float p[4];
#pragma unroll
            for (int r = 0; r < 4; r++) {
                float sv = s[j][r];
                if (masked) {
                    const int key = k0 + 32*(j & 1) + 8*quad + 4*(j >> 1) + r;
                    const float km = kpm[b*Sq + key] ? -1e30f : 0.0f;
                    sv += (am[(size_t)q*Sq + key] + km) * LOG2E;
                }
                p[r] = exp2f(sv);
            }
            lsum += (p[0]+p[1]) + (p[2]+p[3]);
            pk[j][0] = pkbf(p[0], p[1]);
            pk[j][1] = pkbf(p[2], p[3]);
        }

        // PV: O^T += V^T · P^T — P^T B-frag is lane-local by construction:
        // lane needs keys ks*32 + quad*8 + e  ==  {pk[ks], pk[ks+2]}
#pragma unroll
        for (int ks = 0; ks < 2; ks++) {
            union { int i[4]; bhalf8 v; } bp;
            bp.i[0] = pk[ks][0];
            bp.i[1] = pk[ks][1];
            bp.i[2] = pk[ks + 2][0];
            bp.i[3] = pk[ks + 2][1];
            bhalf8 av[4];
#pragma unroll
            for (int nd = 0; nd < 4; nd++)
                av[nd] = *(const bhalf8*)&Vs[ks*2048 + nd*512 + l*8];
#pragma unroll
            for (int nd = 0; nd < 4; nd++)
                o[nd] = __builtin_amdgcn_mfma_f32_16x16x32_bf16(av[nd], bp.v, o[nd], 0,0,0);
        }
    }

    lsum += __shfl_xor(lsum, 16, 64);
    lsum += __shfl_xor(lsum, 32, 64);
    const float rl = 1.0f / lsum;
    if (quad == 0) rlbuf[(size_t)bh*Sq + q] = rl;

#pragma unroll
    for (int nd = 0; nd < 4; nd++) {
        union { __hip_bfloat16 hx[4]; uint2 u; } ou;
#pragma unroll
        for (int r = 0; r < 4; r++) ou.hx[r] = __float2bfloat16(o[nd][r] * rl);
        *(uint2*)(wa + ((size_t)b*Sq + q)*Ee + h*Dd + nd*16 + quad*4) = ou.u;
    }
}

// ---------------- attn_mean: 64q x 64k, reg-staged K (contiguous), direct-global Q ----------------
// Wave w owns q rows [q0 + w*16, +16). K tile (8KB) staged via contiguous uint4
// reads + ds_write to frag-major tile_off layout (shared by 4 waves). Q frags
// read directly from global (private per wave, L2-hot). Live regs ~60: no spill.
__global__ __launch_bounds__(256, 4) void attn_mean_k(
    const __hip_bfloat16* __restrict__ Qp, const __hip_bfloat16* __restrict__ Kp,
    const float* __restrict__ am, const unsigned char* __restrict__ kpm,
    const unsigned int* __restrict__ flag,
    const float* __restrict__ rlbuf, float* __restrict__ attn_mean)
{
    __shared__ __align__(16) __hip_bfloat16 Ks[4096];   // 64 keys x 64 d, frag-major
    const int t = threadIdx.x;
    const int w = t >> 6, l = t & 63, lm = l & 15, quad = l >> 4;
    const int b  = blockIdx.z;
    const int q0 = blockIdx.y * 64;
    const int kc = blockIdx.x * 64;
    const bool masked = (flag[0] != 0u);

    const int off0 = tile_off(t), off1 = tile_off(t + 256);
    const int qrow = q0 + w*16 + lm;

    float macc[4][4] = {};
    const float* rlp = rlbuf + (size_t)(b*Hh)*Sq + q0 + w*16 + quad*4;

    for (int h = 0; h < Hh; h++) {
        const __hip_bfloat16* kg = Kp + ((size_t)(b*Hh + h)*Sq + kc)*Dd;
        const __hip_bfloat16* qg = Qp + (size_t)(b*Hh + h)*Sq*Dd + (size_t)qrow*Dd;
        // contiguous staging reads (issue before barrier; overlap prev compute)
        uint4 kr0 = *(const uint4*)(kg + (size_t)t*8);
        uint4 kr1 = *(const uint4*)(kg + (size_t)(t + 256)*8);
        bhalf8 aq0 = *(const bhalf8*)(qg + quad*8);
        bhalf8 aq1 = *(const bhalf8*)(qg + quad*8 + 32);
        __syncthreads();                      // previous iteration's readers done
        *(uint4*)&Ks[off0] = kr0;
        *(uint4*)&Ks[off1] = kr1;
        __syncthreads();                      // K tile visible

        f32x4 s[4] = {};
#pragma unroll
        for (int j = 0; j < 4; j++) {
            bhalf8 bk = *(const bhalf8*)&Ks[j*512 + l*8];
            s[j] = __builtin_amdgcn_mfma_f32_16x16x32_bf16(aq0, bk, s[j], 0,0,0);
        }
#pragma unroll
        for (int j = 0; j < 4; j++) {
            bhalf8 bk = *(const bhalf8*)&Ks[2048 + j*512 + l*8];
            s[j] = __builtin_amdgcn_mfma_f32_16x16x32_bf16(aq1, bk, s[j], 0,0,0);
        }
        float rl4[4];
#pragma unroll
        for (int r = 0; r < 4; r++) rl4[r] = rlp[(size_t)h*Sq + r] * 0.0625f;
#pragma unroll
        for (int j = 0; j < 4; j++)
#pragma unroll
            for (int r = 0; r < 4; r++) {
                float sv = s[j][r];
                if (masked) {
                    const int key = kc + j*16 + lm;
                    const float km = kpm[b*Sq + key] ? -1e30f : 0.0f;
                    sv += (am[(size_t)(q0 + w*16 + quad*4 + r)*Sq + key] + km) * LOG2E;
                }
                macc[j][r] += exp2f(sv) * rl4[r];
            }
    }
#pragma unroll
    for (int j = 0; j < 4; j++)
#pragma unroll
        for (int r = 0; r < 4; r++)
            attn_mean[((size_t)b*Sq + q0 + w*16 + quad*4 + r)*Sq + kc + j*16 + lm] =
                macc[j][r];
}

// ---------------- GEMM 2: output projection, bf16 MFMA ----------------
__global__ __launch_bounds__(256) void gemm_out(
    const __hip_bfloat16* __restrict__ A, const __hip_bfloat16* __restrict__ Bw,
    const float* __restrict__ bias, float* __restrict__ outp)
{
    __shared__ __align__(16) __hip_bfloat16 As[128*32];
    __shared__ __align__(16) __hip_bfloat16 Bs[128*32];
    const int t = threadIdx.x;
    const int l = t & 63, lm = l & 15, quad = l >> 4;
    const int w = t >> 6;
    const int mw = (w & 1)*64, nw = (w >> 1)*64;
    const int m0 = blockIdx.y*128, n0 = blockIdx.x*128;

    const int srow = t >> 2;
    const int scol = (t & 3)*8;
    const __hip_bfloat16* ag = A  + (size_t)(m0 + srow)*1024 + scol;
    const __hip_bfloat16* bg = Bw + (size_t)(n0 + srow)*1024 + scol;
    __hip_bfloat16* al = As + t*8;
    __hip_bfloat16* bl = Bs + t*8;

    f32x4 acc[4][4] = {};
    for (int k0 = 0; k0 < 1024; k0 += 32) {
        __syncthreads();
        gld16(ag + k0, al);
        gld16(ag + (size_t)64*1024 + k0, al + 2048);
        gld16(bg + k0, bl);
        gld16(bg + (size_t)64*1024 + k0, bl + 2048);
        __syncthreads();
        bhalf8 af[4], bf[4];
#pragma unroll
        for (int i = 0; i < 4; i++) {
            af[i] = *(const bhalf8*)&As[(mw + i*16 + lm)*32 + quad*8];
            bf[i] = *(const bhalf8*)&Bs[(nw + i*16 + lm)*32 + quad*8];
        }
#pragma unroll
        for (int mf = 0; mf < 4; mf++)
#pragma unroll
            for (int nf = 0; nf < 4; nf++)
                acc[mf][nf] = __builtin_amdgcn_mfma_f32_16x16x32_bf16(af[mf], bf[nf], acc[mf][nf], 0,0,0);
    }
#pragma unroll
    for (int nf = 0; nf < 4; nf++) {
        const int n = n0 + nw + nf*16 + lm;
        const float bz = bias[n];
#pragma unroll
        for (int mf = 0; mf < 4; mf++)
#pragma unroll
            for (int r = 0; r < 4; r++) {
                const int m = m0 + mw + mf*16 + quad*4 + r;
                const int b2 = m >> 11, s2 = m & 2047;
                outp[((size_t)s2*Bb + b2)*Ee + n] = acc[mf][nf][r] + bz;
            }
    }
}

extern "C" void kernel_launch(void* const* d_in, const int* in_sizes, int n_in,
                              void* d_out, int out_size, void* d_ws, size_t ws_size,
                              hipStream_t stream) {
    const float*         x         = (const float*)d_in[0];
    const float*         attn_mask = (const float*)d_in[1];
    const unsigned char* kpm       = (const unsigned char*)d_in[2];
    const float*         qkv_w     = (const float*)d_in[3];
    const float*         qkv_b     = (const float*)d_in[4];
    const float*         out_w     = (const float*)d_in[5];
    const float*         out_b     = (const float*)d_in[6];

    float* outp      = (float*)d_out;
    float* attn_mean = outp + 4194304;          // S*B*E

    __hip_bfloat16* xb  = (__hip_bfloat16*)d_ws;     // 8 MB
    __hip_bfloat16* qwb = xb  + 4194304;             // 6 MB
    __hip_bfloat16* owb = qwb + 3145728;             // 2 MB
    __hip_bfloat16* Qp  = owb + 1048576;             // 8 MB (pre-scaled by QSCALE)
    __hip_bfloat16* Kp  = Qp  + 4194304;             // 8 MB
    __hip_bfloat16* Vt  = Kp  + 4194304;             // 8 MB (transposed [B,H,D,S])
    __hip_bfloat16* wab = Vt  + 4194304;             // 8 MB
    float* rlbuf        = (float*)(wab + 4194304);   // 256 KB
    unsigned int* flag  = (unsigned int*)(rlbuf + 65536);

    hipMemsetAsync(flag, 0, sizeof(unsigned int), stream);
    prep_k<<<12288, 256, 0, stream>>>(x, attn_mask, (const unsigned int*)kpm,
                                      qkv_w, out_w, xb, qwb, owb, flag);
    gemm_qkv<<<dim3(24, 32), 256, 0, stream>>>(xb, qwb, qkv_b, Qp, Kp, Vt);
    attn_mfma<<<dim3(1024), 256, 0, stream>>>(Qp, Kp, Vt, attn_mask, kpm, flag, wab, rlbuf);
    attn_mean_k<<<dim3(32, 32, Bb), 256, 0, stream>>>(Qp, Kp, attn_mask, kpm, flag, rlbuf, attn_mean);
    gemm_out<<<dim3(8, 32), 256, 0, stream>>>(wab, owb, out_b, outp);
}

// Round 4
// 464.025 us; speedup vs baseline: 1.4106x; 1.3927x over previous
//
#include <hip/hip_runtime.h>
#include <hip/hip_bf16.h>

// MHA forward, round 10: LDS-free barrier-free attn_mean.
// Rounds 8/9 post-mortem: traffic (FETCH ~505MB = zero-reuse demand) was
// invariant to staging mechanism -> the 2048-block schedule thrashed L2.
// Round 10 returns to the round-7-proven schedule granularity (1024 blocks)
// and loads Q/K MFMA fragments DIRECTLY from global in fragment shape
// (16 rows x 64B segments, L1/L2-hot; all 8 waves share the K tile via L1).
// No LDS, no barriers, no staging VALU, macc=16 regs.
// S=2048 B=2 E=1024 H=16 D=64. scale folded into Q (exp2).
// ws (48.3 MB): xb | qwb | owb | Qp | Kp | Vt | wab | rl | flag
// d_out: out[S,B,E] fp32 (4194304) then attn_mean[B,S,S] fp32 (8388608).

#define Sq 2048
#define Bb 2
#define Ee 1024
#define Hh 16
#define Dd 64
#define LOG2E 1.4426950408889634f
#define QSCALE 0.18033688011112042f   // 0.125 * log2(e)

typedef __attribute__((ext_vector_type(8))) short bhalf8;   // 8 bf16 (4 VGPRs)
typedef __attribute__((ext_vector_type(4))) float f32x4;

__device__ __forceinline__ void gld16(const __hip_bfloat16* g, __hip_bfloat16* l) {
    __builtin_amdgcn_global_load_lds(
        (const __attribute__((address_space(1))) unsigned int*)g,
        (__attribute__((address_space(3))) unsigned int*)l, 16, 0, 0);
}

__device__ __forceinline__ int pkbf(float a, float b) {
    union { __hip_bfloat16 h[2]; int i; } u;
    u.h[0] = __float2bfloat16(a);
    u.h[1] = __float2bfloat16(b);
    return u.i;
}

// slot s (0..511, 16B chunks of a 64x64 bf16 tile, global-linear) -> swizzled
// frag-major LDS elem offset [f|ks][j|nd][quad][lm][8]
__device__ __forceinline__ int tile_off(int s) {
    return ((s >> 2) & 1) * 2048 + (s >> 7) * 512 + (s & 3) * 128 + ((s >> 3) & 15) * 8;
}

// K row permutation: LDS tile row position p holds global key kperm(p).
// p = j*16 + quad*4 + r  ->  key = 32*(j&1) + 8*quad + 4*(j>>1) + r
// so that the QK^T C-registers directly form the PV B-fragment (no shuffles).
__device__ __forceinline__ int kperm(int p) {
    return (p & 3) | (((p >> 5) & 1) << 2) | ((p & 12) << 1) | (((p >> 4) & 1) << 5);
}

// ---------------- fused prep: mask scan + fp32->bf16 conversions ----------------
__global__ __launch_bounds__(256) void prep_k(
    const float* __restrict__ x, const float* __restrict__ am,
    const unsigned int* __restrict__ kpm32,
    const float* __restrict__ qkv_w, const float* __restrict__ out_w,
    __hip_bfloat16* __restrict__ xb, __hip_bfloat16* __restrict__ qwb,
    __hip_bfloat16* __restrict__ owb, unsigned int* __restrict__ flag)
{
    const long i = (long)blockIdx.x*256 + threadIdx.x;
    if (i < 1048576) {                       // mask scan (am 1M float4, kpm 1024 u32)
        float4 v = ((const float4*)am)[i];
        bool nz = (v.x != 0.f) | (v.y != 0.f) | (v.z != 0.f) | (v.w != 0.f);
        if (i < 1024) nz |= (kpm32[i] != 0u);
        if (__ballot(nz)) { if ((threadIdx.x & 63) == 0) atomicOr(flag, 1u); }
    } else if (i < 2097152) {                // x conv with [S,B,E]->[B*S][E]
        const long j = i - 1048576;
        const int m = (int)(j >> 8), e4 = (int)(j & 255);
        const int b = m >> 11, s = m & 2047;
        float4 v = ((const float4*)x)[(size_t)(s*Bb + b)*256 + e4];
        union { __hip_bfloat16 h[4]; uint2 u; } o;
        o.h[0]=__float2bfloat16(v.x); o.h[1]=__float2bfloat16(v.y);
        o.h[2]=__float2bfloat16(v.z); o.h[3]=__float2bfloat16(v.w);
        ((uint2*)xb)[(size_t)m*256 + e4] = o.u;
    } else if (i < 2883584) {                // qkv_w conv (786432 float4)
        const long j = i - 2097152;
        float4 v = ((const float4*)qkv_w)[j];
        union { __hip_bfloat16 h[4]; uint2 u; } o;
        o.h[0]=__float2bfloat16(v.x); o.h[1]=__float2bfloat16(v.y);
        o.h[2]=__float2bfloat16(v.z); o.h[3]=__float2bfloat16(v.w);
        ((uint2*)qwb)[j] = o.u;
    } else if (i < 3145728) {                // out_w conv (262144 float4)
        const long j = i - 2883584;
        float4 v = ((const float4*)out_w)[j];
        union { __hip_bfloat16 h[4]; uint2 u; } o;
        o.h[0]=__float2bfloat16(v.x); o.h[1]=__float2bfloat16(v.y);
        o.h[2]=__float2bfloat16(v.z); o.h[3]=__float2bfloat16(v.w);
        ((uint2*)owb)[j] = o.u;
    }
}

// ---------------- GEMM 1: QKV projection, bf16 MFMA, scatter epilogue ----------------
// Q stored pre-scaled by QSCALE.
__global__ __launch_bounds__(256) void gemm_qkv(
    const __hip_bfloat16* __restrict__ A, const __hip_bfloat16* __restrict__ Bw,
    const float* __restrict__ bias,
    __hip_bfloat16* __restrict__ Qp, __hip_bfloat16* __restrict__ Kp,
    __hip_bfloat16* __restrict__ Vt)
{
    __shared__ __align__(16) __hip_bfloat16 As[128*32];
    __shared__ __align__(16) __hip_bfloat16 Bs[128*32];
    const int t = threadIdx.x;
    const int l = t & 63, lm = l & 15, quad = l >> 4;
    const int w = t >> 6;
    const int mw = (w & 1)*64, nw = (w >> 1)*64;
    const int m0 = blockIdx.y*128, n0 = blockIdx.x*128;

    const int srow = t >> 2;              // 0..63
    const int scol = (t & 3)*8;
    const __hip_bfloat16* ag = A  + (size_t)(m0 + srow)*1024 + scol;
    const __hip_bfloat16* bg = Bw + (size_t)(n0 + srow)*1024 + scol;
    __hip_bfloat16* al = As + t*8;
    __hip_bfloat16* bl = Bs + t*8;

    f32x4 acc[4][4] = {};
    for (int k0 = 0; k0 < 1024; k0 += 32) {
        __syncthreads();
        gld16(ag + k0, al);
        gld16(ag + (size_t)64*1024 + k0, al + 2048);
        gld16(bg + k0, bl);
        gld16(bg + (size_t)64*1024 + k0, bl + 2048);
        __syncthreads();
        bhalf8 af[4], bf[4];
#pragma unroll
        for (int i = 0; i < 4; i++) {
            af[i] = *(const bhalf8*)&As[(mw + i*16 + lm)*32 + quad*8];
            bf[i] = *(const bhalf8*)&Bs[(nw + i*16 + lm)*32 + quad*8];
        }
#pragma unroll
        for (int mf = 0; mf < 4; mf++)
#pragma unroll
            for (int nf = 0; nf < 4; nf++)
                acc[mf][nf] = __builtin_amdgcn_mfma_f32_16x16x32_bf16(af[mf], bf[nf], acc[mf][nf], 0,0,0);
    }
#pragma unroll
    for (int nf = 0; nf < 4; nf++) {
        const int n = n0 + nw + nf*16 + lm;
        const float bz = bias[n];
        const int which = n >> 10, hh = (n >> 6) & 15, dd = n & 63;
#pragma unroll
        for (int mf = 0; mf < 4; mf++)
#pragma unroll
            for (int r = 0; r < 4; r++) {
                const int m = m0 + mw + mf*16 + quad*4 + r;
                const int b2 = m >> 11, s2 = m & 2047;
                const float vf = acc[mf][nf][r] + bz;
                if (which == 0)
                    Qp[((size_t)(b2*Hh + hh)*Sq + s2)*Dd + dd] = __float2bfloat16(vf * QSCALE);
                else if (which == 1)
                    Kp[((size_t)(b2*Hh + hh)*Sq + s2)*Dd + dd] = __float2bfloat16(vf);
                else
                    Vt[((size_t)(b2*Hh + hh)*Dd + dd)*Sq + s2] = __float2bfloat16(vf);
            }
    }
}

// ---------------- Attention core: LDS-staged tiles, XCD-pinned, shuffle-free PV ----------------
// blk = xcd + 8*qt + 256*grp ; bh = grp*8 + xcd. Block = 4 waves x 16 q rows.
// Per kt: K tile (8KB) + V^T tile (8KB) staged into swizzled frag-major LDS.
// K rows are permuted at the GLOBAL source (kperm) so that the QK^T output
// registers directly form the PV B-fragment: no ds_bpermute in the PV step.
__global__ __launch_bounds__(256, 4) void attn_mfma(
    const __hip_bfloat16* __restrict__ Qp, const __hip_bfloat16* __restrict__ Kp,
    const __hip_bfloat16* __restrict__ Vt,
    const float* __restrict__ am, const unsigned char* __restrict__ kpm,
    const unsigned int* __restrict__ flag,
    __hip_bfloat16* __restrict__ wa, float* __restrict__ rlbuf)
{
    __shared__ __align__(16) __hip_bfloat16 Ks[4096];
    __shared__ __align__(16) __hip_bfloat16 Vs[4096];
    const int t = threadIdx.x;
    const int w = t >> 6, l = t & 63, lm = l & 15, quad = l >> 4;
    const int blk = blockIdx.x;
    const int xcd = blk & 7;
    const int qt  = (blk >> 3) & 31;
    const int grp = blk >> 8;                  // 0..3
    const int bh  = grp*8 + xcd;
    const int b   = bh >> 4, h = bh & 15;
    const int q   = qt*64 + w*16 + lm;
    const bool masked = (flag[0] != 0u);

    const __hip_bfloat16* qbase = Qp + (size_t)bh*Sq*Dd;
    const __hip_bfloat16* kbase = Kp + (size_t)bh*Sq*Dd;
    const __hip_bfloat16* vbase = Vt + (size_t)bh*Dd*Sq;

    // Q as B-operand (pre-scaled), one-time strided load
    bhalf8 bq[2];
    bq[0] = *(const bhalf8*)(qbase + (size_t)q*Dd + quad*8);
    bq[1] = *(const bhalf8*)(qbase + (size_t)q*Dd + quad*8 + 32);

    f32x4 o[4] = {};
    float lsum = 0.f;

    // LDS write offsets for this thread's two slots (linear, conflict-free)
    const int off0 = tile_off(t), off1 = tile_off(t + 256);
    // permuted global K rows feeding those slots
    const int krow0 = kperm(t >> 3);
    const int krow1 = kperm(32 + (t >> 3));
    const int kcol  = (t & 7)*8;

    // preload tile 0 staging regs
    uint4 kreg0 = *(const uint4*)(kbase + (size_t)krow0*Dd + kcol);
    uint4 kreg1 = *(const uint4*)(kbase + (size_t)krow1*Dd + kcol);
    uint4 vreg0 = *(const uint4*)(vbase + (size_t)(t >> 3)*Sq + (t & 7)*8);
    uint4 vreg1 = *(const uint4*)(vbase + (size_t)((t + 256) >> 3)*Sq + (t & 7)*8);

    for (int kt = 0; kt < 32; kt++) {
        __syncthreads();                       // previous tile's readers done
        *(uint4*)&Ks[off0] = kreg0;
        *(uint4*)&Ks[off1] = kreg1;
        *(uint4*)&Vs[off0] = vreg0;
        *(uint4*)&Vs[off1] = vreg1;
        if (kt < 31) {                         // prefetch tile kt+1
            const int kn = (kt + 1)*64;
            kreg0 = *(const uint4*)(kbase + (size_t)(kn + krow0)*Dd + kcol);
            kreg1 = *(const uint4*)(kbase + (size_t)(kn + krow1)*Dd + kcol);
            vreg0 = *(const uint4*)(vbase + (size_t)(t >> 3)*Sq + kn + (t & 7)*8);
            vreg1 = *(const uint4*)(vbase + (size_t)((t + 256) >> 3)*Sq + kn + (t & 7)*8);
        }
        __syncthreads();                       // tile kt visible

        const int k0 = kt*64;
        // S^T = K · Q^T  (K rows permuted: row p holds key kperm(p))
        f32x4 s[4] = {};
#pragma unroll
        for (int f = 0; f < 2; f++) {
            bhalf8 ak[4];
#pragma unroll
            for (int j = 0; j < 4; j++)
                ak[j] = *(const bhalf8*)&Ks[f*2048 + j*512 + l*8];
#pragma unroll
            for (int j = 0; j < 4; j++)
                s[j] = __builtin_amdgcn_mfma_f32_16x16x32_bf16(ak[j], bq[f], s[j], 0,0,0);
        }

        // exp2 + pack; s[j][r] is key k0 + 32*(j&1) + 8*quad + 4*(j>>1) + r
        int pk[4][2];
#pragma unroll
        for (int j = 0; j < 4; j++) {
            float p[4];
#pragma unroll
            for (int r = 0; r < 4; r++) {
                float sv = s[j][r];
                if (masked) {
                    const int key = k0 + 32*(j & 1) + 8*quad + 4*(j >> 1) + r;
                    const float km = kpm[b*Sq + key] ? -1e30f : 0.0f;
                    sv += (am[(size_t)q*Sq + key] + km) * LOG2E;
                }
                p[r] = exp2f(sv);
            }
            lsum += (p[0]+p[1]) + (p[2]+p[3]);
            pk[j][0] = pkbf(p[0], p[1]);
            pk[j][1] = pkbf(p[2], p[3]);
        }

        // PV: O^T += V^T · P^T — P^T B-frag is lane-local by construction:
        // lane needs keys ks*32 + quad*8 + e  ==  {pk[ks], pk[ks+2]}
#pragma unroll
        for (int ks = 0; ks < 2; ks++) {
            union { int i[4]; bhalf8 v; } bp;
            bp.i[0] = pk[ks][0];
            bp.i[1] = pk[ks][1];
            bp.i[2] = pk[ks + 2][0];
            bp.i[3] = pk[ks + 2][1];
            bhalf8 av[4];
#pragma unroll
            for (int nd = 0; nd < 4; nd++)
                av[nd] = *(const bhalf8*)&Vs[ks*2048 + nd*512 + l*8];
#pragma unroll
            for (int nd = 0; nd < 4; nd++)
                o[nd] = __builtin_amdgcn_mfma_f32_16x16x32_bf16(av[nd], bp.v, o[nd], 0,0,0);
        }
    }

    lsum += __shfl_xor(lsum, 16, 64);
    lsum += __shfl_xor(lsum, 32, 64);
    const float rl = 1.0f / lsum;
    if (quad == 0) rlbuf[(size_t)bh*Sq + q] = rl;

#pragma unroll
    for (int nd = 0; nd < 4; nd++) {
        union { __hip_bfloat16 hx[4]; uint2 u; } ou;
#pragma unroll
        for (int r = 0; r < 4; r++) ou.hx[r] = __float2bfloat16(o[nd][r] * rl);
        *(uint2*)(wa + ((size_t)b*Sq + q)*Ee + h*Dd + nd*16 + quad*4) = ou.u;
    }
}

// ---------------- attn_mean: LDS-free, barrier-free, direct fragment loads ----------------
// Grid (32 kc, 16 q0, 2 b), 512 threads = 8 waves; wave w owns q rows
// [q0 + w*16, +16). Per h: Q A-frags (2) and K B-frags (8) loaded directly
// from global in fragment shape (lane lm -> row, quad -> 16B chunk); the 8KB
// K tile is shared across the 8 waves through L1. macc[4][4]=16 regs.
__global__ __launch_bounds__(512, 2) void attn_mean_k(
    const __hip_bfloat16* __restrict__ Qp, const __hip_bfloat16* __restrict__ Kp,
    const float* __restrict__ am, const unsigned char* __restrict__ kpm,
    const unsigned int* __restrict__ flag,
    const float* __restrict__ rlbuf, float* __restrict__ attn_mean)
{
    const int t = threadIdx.x;
    const int w = t >> 6, l = t & 63, lm = l & 15, quad = l >> 4;
    const int b  = blockIdx.z;
    const int q0 = blockIdx.y * 128;
    const int kc = blockIdx.x * 64;
    const bool masked = (flag[0] != 0u);
    const int qa = q0 + w*16 + lm;          // A-frag row (this lane)
    const int qc = q0 + w*16 + quad*4;      // C-rows base (this lane)

    float macc[4][4] = {};

    for (int h = 0; h < Hh; h++) {
        const size_t base = (size_t)(b*Hh + h)*Sq;
        const __hip_bfloat16* qg = Qp + (base + qa)*Dd + quad*8;
        const __hip_bfloat16* kg = Kp + (base + kc + lm)*Dd + quad*8;
        f32x4 s[4] = {};
#pragma unroll
        for (int f = 0; f < 2; f++) {
            bhalf8 aq = *(const bhalf8*)(qg + f*32);
#pragma unroll
            for (int j = 0; j < 4; j++) {
                bhalf8 bk = *(const bhalf8*)(kg + (size_t)(j*16)*Dd + f*32);
                s[j] = __builtin_amdgcn_mfma_f32_16x16x32_bf16(aq, bk, s[j], 0,0,0);
            }
        }
        const f32x4 rl4 = *(const f32x4*)(rlbuf + base + qc);
#pragma unroll
        for (int j = 0; j < 4; j++)
#pragma unroll
            for (int r = 0; r < 4; r++) {
                float sv = s[j][r];
                if (masked) {
                    const int key = kc + j*16 + lm;
                    const float km = kpm[b*Sq + key] ? -1e30f : 0.0f;
                    sv += (am[(size_t)(qc + r)*Sq + key] + km) * LOG2E;
                }
                macc[j][r] += exp2f(sv) * (rl4[r] * 0.0625f);
            }
    }
#pragma unroll
    for (int j = 0; j < 4; j++)
#pragma unroll
        for (int r = 0; r < 4; r++)
            attn_mean[((size_t)b*Sq + qc + r)*Sq + kc + j*16 + lm] = macc[j][r];
}

// ---------------- GEMM 2: output projection, bf16 MFMA ----------------
__global__ __launch_bounds__(256) void gemm_out(
    const __hip_bfloat16* __restrict__ A, const __hip_bfloat16* __restrict__ Bw,
    const float* __restrict__ bias, float* __restrict__ outp)
{
    __shared__ __align__(16) __hip_bfloat16 As[128*32];
    __shared__ __align__(16) __hip_bfloat16 Bs[128*32];
    const int t = threadIdx.x;
    const int l = t & 63, lm = l & 15, quad = l >> 4;
    const int w = t >> 6;
    const int mw = (w & 1)*64, nw = (w >> 1)*64;
    const int m0 = blockIdx.y*128, n0 = blockIdx.x*128;

    const int srow = t >> 2;
    const int scol = (t & 3)*8;
    const __hip_bfloat16* ag = A  + (size_t)(m0 + srow)*1024 + scol;
    const __hip_bfloat16* bg = Bw + (size_t)(n0 + srow)*1024 + scol;
    __hip_bfloat16* al = As + t*8;
    __hip_bfloat16* bl = Bs + t*8;

    f32x4 acc[4][4] = {};
    for (int k0 = 0; k0 < 1024; k0 += 32) {
        __syncthreads();
        gld16(ag + k0, al);
        gld16(ag + (size_t)64*1024 + k0, al + 2048);
        gld16(bg + k0, bl);
        gld16(bg + (size_t)64*1024 + k0, bl + 2048);
        __syncthreads();
        bhalf8 af[4], bf[4];
#pragma unroll
        for (int i = 0; i < 4; i++) {
            af[i] = *(const bhalf8*)&As[(mw + i*16 + lm)*32 + quad*8];
            bf[i] = *(const bhalf8*)&Bs[(nw + i*16 + lm)*32 + quad*8];
        }
#pragma unroll
        for (int mf = 0; mf < 4; mf++)
#pragma unroll
            for (int nf = 0; nf < 4; nf++)
                acc[mf][nf] = __builtin_amdgcn_mfma_f32_16x16x32_bf16(af[mf], bf[nf], acc[mf][nf], 0,0,0);
    }
#pragma unroll
    for (int nf = 0; nf < 4; nf++) {
        const int n = n0 + nw + nf*16 + lm;
        const float bz = bias[n];
#pragma unroll
        for (int mf = 0; mf < 4; mf++)
#pragma unroll
            for (int r = 0; r < 4; r++) {
                const int m = m0 + mw + mf*16 + quad*4 + r;
                const int b2 = m >> 11, s2 = m & 2047;
                outp[((size_t)s2*Bb + b2)*Ee + n] = acc[mf][nf][r] + bz;
            }
    }
}

extern "C" void kernel_launch(void* const* d_in, const int* in_sizes, int n_in,
                              void* d_out, int out_size, void* d_ws, size_t ws_size,
                              hipStream_t stream) {
    const float*         x         = (const float*)d_in[0];
    const float*         attn_mask = (const float*)d_in[1];
    const unsigned char* kpm       = (const unsigned char*)d_in[2];
    const float*         qkv_w     = (const float*)d_in[3];
    const float*         qkv_b     = (const float*)d_in[4];
    const float*         out_w     = (const float*)d_in[5];
    const float*         out_b     = (const float*)d_in[6];

    float* outp      = (float*)d_out;
    float* attn_mean = outp + 4194304;          // S*B*E

    __hip_bfloat16* xb  = (__hip_bfloat16*)d_ws;     // 8 MB
    __hip_bfloat16* qwb = xb  + 4194304;             // 6 MB
    __hip_bfloat16* owb = qwb + 3145728;             // 2 MB
    __hip_bfloat16* Qp  = owb + 1048576;             // 8 MB (pre-scaled by QSCALE)
    __hip_bfloat16* Kp  = Qp  + 4194304;             // 8 MB
    __hip_bfloat16* Vt  = Kp  + 4194304;             // 8 MB (transposed [B,H,D,S])
    __hip_bfloat16* wab = Vt  + 4194304;             // 8 MB
    float* rlbuf        = (float*)(wab + 4194304);   // 256 KB
    unsigned int* flag  = (unsigned int*)(rlbuf + 65536);

    hipMemsetAsync(flag, 0, sizeof(unsigned int), stream);
    prep_k<<<12288, 256, 0, stream>>>(x, attn_mask, (const unsigned int*)kpm,
                                      qkv_w, out_w, xb, qwb, owb, flag);
    gemm_qkv<<<dim3(24, 32), 256, 0, stream>>>(xb, qwb, qkv_b, Qp, Kp, Vt);
    attn_mfma<<<dim3(1024), 256, 0, stream>>>(Qp, Kp, Vt, attn_mask, kpm, flag, wab, rlbuf);
    attn_mean_k<<<dim3(32, 16, Bb), 512, 0, stream>>>(Qp, Kp, attn_mask, kpm, flag, rlbuf, attn_mean);
    gemm_out<<<dim3(8, 32), 256, 0, stream>>>(wab, owb, out_b, outp);
}

// Round 5
// 341.349 us; speedup vs baseline: 1.9175x; 1.3594x over previous
//
#include <hip/hip_runtime.h>
#include <hip/hip_bf16.h>

// MHA forward, round 11: attn_mean = round-7 structure minus its two defects.
// Rounds 7/9/10 all spilled (excess WRITE_SIZE = scratch round-trips). Round 11
// keeps the only proven schedule (1024 blocks, 128q x 64k, h-loop, K tile in
// frag-major LDS via contiguous reg-stage) and removes the pressure sources:
// Q read directly from global in fragment shape (no Q LDS, no qoff conflicts),
// no bk[8] hoisting, no occupancy clamp (launch_bounds(256) only), K-only
// prefetch. 1D grid XCD-pinned so kc-blocks sharing a Q slice stay on one XCD.
// S=2048 B=2 E=1024 H=16 D=64. scale folded into Q (exp2).
// ws (48.3 MB): xb | qwb | owb | Qp | Kp | Vt | wab | rl | flag
// d_out: out[S,B,E] fp32 (4194304) then attn_mean[B,S,S] fp32 (8388608).

#define Sq 2048
#define Bb 2
#define Ee 1024
#define Hh 16
#define Dd 64
#define LOG2E 1.4426950408889634f
#define QSCALE 0.18033688011112042f   // 0.125 * log2(e)

typedef __attribute__((ext_vector_type(8))) short bhalf8;   // 8 bf16 (4 VGPRs)
typedef __attribute__((ext_vector_type(4))) float f32x4;

__device__ __forceinline__ void gld16(const __hip_bfloat16* g, __hip_bfloat16* l) {
    __builtin_amdgcn_global_load_lds(
        (const __attribute__((address_space(1))) unsigned int*)g,
        (__attribute__((address_space(3))) unsigned int*)l, 16, 0, 0);
}

__device__ __forceinline__ int pkbf(float a, float b) {
    union { __hip_bfloat16 h[2]; int i; } u;
    u.h[0] = __float2bfloat16(a);
    u.h[1] = __float2bfloat16(b);
    return u.i;
}

// slot s (0..511, 16B chunks of a 64x64 bf16 tile, global-linear) -> swizzled
// frag-major LDS elem offset [f|ks][j|nd][quad][lm][8]
__device__ __forceinline__ int tile_off(int s) {
    return ((s >> 2) & 1) * 2048 + (s >> 7) * 512 + (s & 3) * 128 + ((s >> 3) & 15) * 8;
}

// K row permutation: LDS tile row position p holds global key kperm(p).
// p = j*16 + quad*4 + r  ->  key = 32*(j&1) + 8*quad + 4*(j>>1) + r
// so that the QK^T C-registers directly form the PV B-fragment (no shuffles).
__device__ __forceinline__ int kperm(int p) {
    return (p & 3) | (((p >> 5) & 1) << 2) | ((p & 12) << 1) | (((p >> 4) & 1) << 5);
}

// ---------------- fused prep: mask scan + fp32->bf16 conversions ----------------
__global__ __launch_bounds__(256) void prep_k(
    const float* __restrict__ x, const float* __restrict__ am,
    const unsigned int* __restrict__ kpm32,
    const float* __restrict__ qkv_w, const float* __restrict__ out_w,
    __hip_bfloat16* __restrict__ xb, __hip_bfloat16* __restrict__ qwb,
    __hip_bfloat16* __restrict__ owb, unsigned int* __restrict__ flag)
{
    const long i = (long)blockIdx.x*256 + threadIdx.x;
    if (i < 1048576) {                       // mask scan (am 1M float4, kpm 1024 u32)
        float4 v = ((const float4*)am)[i];
        bool nz = (v.x != 0.f) | (v.y != 0.f) | (v.z != 0.f) | (v.w != 0.f);
        if (i < 1024) nz |= (kpm32[i] != 0u);
        if (__ballot(nz)) { if ((threadIdx.x & 63) == 0) atomicOr(flag, 1u); }
    } else if (i < 2097152) {                // x conv with [S,B,E]->[B*S][E]
        const long j = i - 1048576;
        const int m = (int)(j >> 8), e4 = (int)(j & 255);
        const int b = m >> 11, s = m & 2047;
        float4 v = ((const float4*)x)[(size_t)(s*Bb + b)*256 + e4];
        union { __hip_bfloat16 h[4]; uint2 u; } o;
        o.h[0]=__float2bfloat16(v.x); o.h[1]=__float2bfloat16(v.y);
        o.h[2]=__float2bfloat16(v.z); o.h[3]=__float2bfloat16(v.w);
        ((uint2*)xb)[(size_t)m*256 + e4] = o.u;
    } else if (i < 2883584) {                // qkv_w conv (786432 float4)
        const long j = i - 2097152;
        float4 v = ((const float4*)qkv_w)[j];
        union { __hip_bfloat16 h[4]; uint2 u; } o;
        o.h[0]=__float2bfloat16(v.x); o.h[1]=__float2bfloat16(v.y);
        o.h[2]=__float2bfloat16(v.z); o.h[3]=__float2bfloat16(v.w);
        ((uint2*)qwb)[j] = o.u;
    } else if (i < 3145728) {                // out_w conv (262144 float4)
        const long j = i - 2883584;
        float4 v = ((const float4*)out_w)[j];
        union { __hip_bfloat16 h[4]; uint2 u; } o;
        o.h[0]=__float2bfloat16(v.x); o.h[1]=__float2bfloat16(v.y);
        o.h[2]=__float2bfloat16(v.z); o.h[3]=__float2bfloat16(v.w);
        ((uint2*)owb)[j] = o.u;
    }
}

// ---------------- GEMM 1: QKV projection, bf16 MFMA, scatter epilogue ----------------
// Q stored pre-scaled by QSCALE.
__global__ __launch_bounds__(256) void gemm_qkv(
    const __hip_bfloat16* __restrict__ A, const __hip_bfloat16* __restrict__ Bw,
    const float* __restrict__ bias,
    __hip_bfloat16* __restrict__ Qp, __hip_bfloat16* __restrict__ Kp,
    __hip_bfloat16* __restrict__ Vt)
{
    __shared__ __align__(16) __hip_bfloat16 As[128*32];
    __shared__ __align__(16) __hip_bfloat16 Bs[128*32];
    const int t = threadIdx.x;
    const int l = t & 63, lm = l & 15, quad = l >> 4;
    const int w = t >> 6;
    const int mw = (w & 1)*64, nw = (w >> 1)*64;
    const int m0 = blockIdx.y*128, n0 = blockIdx.x*128;

    const int srow = t >> 2;              // 0..63
    const int scol = (t & 3)*8;
    const __hip_bfloat16* ag = A  + (size_t)(m0 + srow)*1024 + scol;
    const __hip_bfloat16* bg = Bw + (size_t)(n0 + srow)*1024 + scol;
    __hip_bfloat16* al = As + t*8;
    __hip_bfloat16* bl = Bs + t*8;

    f32x4 acc[4][4] = {};
    for (int k0 = 0; k0 < 1024; k0 += 32) {
        __syncthreads();
        gld16(ag + k0, al);
        gld16(ag + (size_t)64*1024 + k0, al + 2048);
        gld16(bg + k0, bl);
        gld16(bg + (size_t)64*1024 + k0, bl + 2048);
        __syncthreads();
        bhalf8 af[4], bf[4];
#pragma unroll
        for (int i = 0; i < 4; i++) {
            af[i] = *(const bhalf8*)&As[(mw + i*16 + lm)*32 + quad*8];
            bf[i] = *(const bhalf8*)&Bs[(nw + i*16 + lm)*32 + quad*8];
        }
#pragma unroll
        for (int mf = 0; mf < 4; mf++)
#pragma unroll
            for (int nf = 0; nf < 4; nf++)
                acc[mf][nf] = __builtin_amdgcn_mfma_f32_16x16x32_bf16(af[mf], bf[nf], acc[mf][nf], 0,0,0);
    }
#pragma unroll
    for (int nf = 0; nf < 4; nf++) {
        const int n = n0 + nw + nf*16 + lm;
        const float bz = bias[n];
        const int which = n >> 10, hh = (n >> 6) & 15, dd = n & 63;
#pragma unroll
        for (int mf = 0; mf < 4; mf++)
#pragma unroll
            for (int r = 0; r < 4; r++) {
                const int m = m0 + mw + mf*16 + quad*4 + r;
                const int b2 = m >> 11, s2 = m & 2047;
                const float vf = acc[mf][nf][r] + bz;
                if (which == 0)
                    Qp[((size_t)(b2*Hh + hh)*Sq + s2)*Dd + dd] = __float2bfloat16(vf * QSCALE);
                else if (which == 1)
                    Kp[((size_t)(b2*Hh + hh)*Sq + s2)*Dd + dd] = __float2bfloat16(vf);
                else
                    Vt[((size_t)(b2*Hh + hh)*Dd + dd)*Sq + s2] = __float2bfloat16(vf);
            }
    }
}

// ---------------- Attention core: LDS-staged tiles, XCD-pinned, shuffle-free PV ----------------
// blk = xcd + 8*qt + 256*grp ; bh = grp*8 + xcd. Block = 4 waves x 16 q rows.
// Per kt: K tile (8KB) + V^T tile (8KB) staged into swizzled frag-major LDS.
// K rows are permuted at the GLOBAL source (kperm) so that the QK^T output
// registers directly form the PV B-fragment: no ds_bpermute in the PV step.
__global__ __launch_bounds__(256, 4) void attn_mfma(
    const __hip_bfloat16* __restrict__ Qp, const __hip_bfloat16* __restrict__ Kp,
    const __hip_bfloat16* __restrict__ Vt,
    const float* __restrict__ am, const unsigned char* __restrict__ kpm,
    const unsigned int* __restrict__ flag,
    __hip_bfloat16* __restrict__ wa, float* __restrict__ rlbuf)
{
    __shared__ __align__(16) __hip_bfloat16 Ks[4096];
    __shared__ __align__(16) __hip_bfloat16 Vs[4096];
    const int t = threadIdx.x;
    const int w = t >> 6, l = t & 63, lm = l & 15, quad = l >> 4;
    const int blk = blockIdx.x;
    const int xcd = blk & 7;
    const int qt  = (blk >> 3) & 31;
    const int grp = blk >> 8;                  // 0..3
    const int bh  = grp*8 + xcd;
    const int b   = bh >> 4, h = bh & 15;
    const int q   = qt*64 + w*16 + lm;
    const bool masked = (flag[0] != 0u);

    const __hip_bfloat16* qbase = Qp + (size_t)bh*Sq*Dd;
    const __hip_bfloat16* kbase = Kp + (size_t)bh*Sq*Dd;
    const __hip_bfloat16* vbase = Vt + (size_t)bh*Dd*Sq;

    // Q as B-operand (pre-scaled), one-time strided load
    bhalf8 bq[2];
    bq[0] = *(const bhalf8*)(qbase + (size_t)q*Dd + quad*8);
    bq[1] = *(const bhalf8*)(qbase + (size_t)q*Dd + quad*8 + 32);

    f32x4 o[4] = {};
    float lsum = 0.f;

    // LDS write offsets for this thread's two slots (linear, conflict-free)
    const int off0 = tile_off(t), off1 = tile_off(t + 256);
    // permuted global K rows feeding those slots
    const int krow0 = kperm(t >> 3);
    const int krow1 = kperm(32 + (t >> 3));
    const int kcol  = (t & 7)*8;

    // preload tile 0 staging regs
    uint4 kreg0 = *(const uint4*)(kbase + (size_t)krow0*Dd + kcol);
    uint4 kreg1 = *(const uint4*)(kbase + (size_t)krow1*Dd + kcol);
    uint4 vreg0 = *(const uint4*)(vbase + (size_t)(t >> 3)*Sq + (t & 7)*8);
    uint4 vreg1 = *(const uint4*)(vbase + (size_t)((t + 256) >> 3)*Sq + (t & 7)*8);

    for (int kt = 0; kt < 32; kt++) {
        __syncthreads();                       // previous tile's readers done
        *(uint4*)&Ks[off0] = kreg0;
        *(uint4*)&Ks[off1] = kreg1;
        *(uint4*)&Vs[off0] = vreg0;
        *(uint4*)&Vs[off1] = vreg1;
        if (kt < 31) {                         // prefetch tile kt+1
            const int kn = (kt + 1)*64;
            kreg0 = *(const uint4*)(kbase + (size_t)(kn + krow0)*Dd + kcol);
            kreg1 = *(const uint4*)(kbase + (size_t)(kn + krow1)*Dd + kcol);
            vreg0 = *(const uint4*)(vbase + (size_t)(t >> 3)*Sq + kn + (t & 7)*8);
            vreg1 = *(const uint4*)(vbase + (size_t)((t + 256) >> 3)*Sq + kn + (t & 7)*8);
        }
        __syncthreads();                       // tile kt visible

        const int k0 = kt*64;
        // S^T = K · Q^T  (K rows permuted: row p holds key kperm(p))
        f32x4 s[4] = {};
#pragma unroll
        for (int f = 0; f < 2; f++) {
            bhalf8 ak[4];
#pragma unroll
            for (int j = 0; j < 4; j++)
                ak[j] = *(const bhalf8*)&Ks[f*2048 + j*512 + l*8];
#pragma unroll
            for (int j = 0; j < 4; j++)
                s[j] = __builtin_amdgcn_mfma_f32_16x16x32_bf16(ak[j], bq[f], s[j], 0,0,0);
        }

        // exp2 + pack; s[j][r] is key k0 + 32*(j&1) + 8*quad + 4*(j>>1) + r
        int pk[4][2];
#pragma unroll
        for (int j = 0; j < 4; j++) {
            float p[4];
#pragma unroll
            for (int r = 0; r < 4; r++) {
                float sv = s[j][r];
                if (masked) {
                    const int key = k0 + 32*(j & 1) + 8*quad + 4*(j >> 1) + r;
                    const float km = kpm[b*Sq + key] ? -1e30f : 0.0f;
                    sv += (am[(size_t)q*Sq + key] + km) * LOG2E;
                }
                p[r] = exp2f(sv);
            }
            lsum += (p[0]+p[1]) + (p[2]+p[3]);
            pk[j][0] = pkbf(p[0], p[1]);
            pk[j][1] = pkbf(p[2], p[3]);
        }

        // PV: O^T += V^T · P^T — P^T B-frag is lane-local by construction:
        // lane needs keys ks*32 + quad*8 + e  ==  {pk[ks], pk[ks+2]}
#pragma unroll
        for (int ks = 0; ks < 2; ks++) {
            union { int i[4]; bhalf8 v; } bp;
            bp.i[0] = pk[ks][0];
            bp.i[1] = pk[ks][1];
            bp.i[2] = pk[ks + 2][0];
            bp.i[3] = pk[ks + 2][1];
            bhalf8 av[4];
#pragma unroll
            for (int nd = 0; nd < 4; nd++)
                av[nd] = *(const bhalf8*)&Vs[ks*2048 + nd*512 + l*8];
#pragma unroll
            for (int nd = 0; nd < 4; nd++)
                o[nd] = __builtin_amdgcn_mfma_f32_16x16x32_bf16(av[nd], bp.v, o[nd], 0,0,0);
        }
    }

    lsum += __shfl_xor(lsum, 16, 64);
    lsum += __shfl_xor(lsum, 32, 64);
    const float rl = 1.0f / lsum;
    if (quad == 0) rlbuf[(size_t)bh*Sq + q] = rl;

#pragma unroll
    for (int nd = 0; nd < 4; nd++) {
        union { __hip_bfloat16 hx[4]; uint2 u; } ou;
#pragma unroll
        for (int r = 0; r < 4; r++) ou.hx[r] = __float2bfloat16(o[nd][r] * rl);
        *(uint2*)(wa + ((size_t)b*Sq + q)*Ee + h*Dd + nd*16 + quad*4) = ou.u;
    }
}

// ---------------- attn_mean: 128q x 64k, K in LDS (contiguous reg-stage), Q direct ----------------
// 1024 blocks x 256 threads (4 waves); wave w owns q rows [q0 + w*32, +32).
// 1D grid XCD-pinned: blk&7 -> q0 low bits so the 32 kc-blocks sharing one Q
// slice run consecutively on one XCD (Q re-reads = that XCD's L2 hits).
// K tile (8KB/h) staged via contiguous uint4 + tile_off ds_write (attn_mfma-
// proven). Q A-frags direct from global. No occupancy clamp: live ~90 VGPR.
__global__ __launch_bounds__(256) void attn_mean_k(
    const __hip_bfloat16* __restrict__ Qp, const __hip_bfloat16* __restrict__ Kp,
    const float* __restrict__ am, const unsigned char* __restrict__ kpm,
    const unsigned int* __restrict__ flag,
    const float* __restrict__ rlbuf, float* __restrict__ attn_mean)
{
    __shared__ __align__(16) __hip_bfloat16 Ks[4096];   // 64 keys x 64 d, frag-major
    const int t = threadIdx.x;
    const int w = t >> 6, l = t & 63, lm = l & 15, quad = l >> 4;
    const int blk = blockIdx.x;
    const int q0idx = (blk & 7) | (((blk >> 8) & 1) << 3);   // 0..15
    const int kc    = ((blk >> 3) & 31) * 64;
    const int b     = (blk >> 9) & 1;
    const int q0    = q0idx * 128;
    const bool masked = (flag[0] != 0u);

    const int off0 = tile_off(t), off1 = tile_off(t + 256);
    const int qa = q0 + w*32;                 // wave's 32 q rows

    float macc[2][4][4] = {};

    // preload h=0 K staging (contiguous)
    {
        const __hip_bfloat16* kg = Kp + ((size_t)(b*Hh)*Sq + kc)*Dd;
        uint4 kr0 = *(const uint4*)(kg + (size_t)t*8);
        uint4 kr1 = *(const uint4*)(kg + (size_t)(t + 256)*8);
        *(uint4*)&Ks[off0] = kr0;
        *(uint4*)&Ks[off1] = kr1;
    }

    for (int h = 0; h < Hh; h++) {
        __syncthreads();                      // K tile for h visible
        const size_t base = (size_t)(b*Hh + h)*Sq;

#pragma unroll
        for (int su = 0; su < 2; su++) {
            const int qrow = qa + su*16;
            const __hip_bfloat16* qg = Qp + (base + qrow + lm)*Dd + quad*8;
            f32x4 s[4] = {};
#pragma unroll
            for (int f = 0; f < 2; f++) {
                bhalf8 aq = *(const bhalf8*)(qg + f*32);
#pragma unroll
                for (int j = 0; j < 4; j++) {
                    bhalf8 bk = *(const bhalf8*)&Ks[f*2048 + j*512 + l*8];
                    s[j] = __builtin_amdgcn_mfma_f32_16x16x32_bf16(aq, bk, s[j], 0,0,0);
                }
            }
            const f32x4 rl4 = *(const f32x4*)(rlbuf + base + qrow + quad*4);
#pragma unroll
            for (int j = 0; j < 4; j++)
#pragma unroll
                for (int r = 0; r < 4; r++) {
                    float sv = s[j][r];
                    if (masked) {
                        const int key = kc + j*16 + lm;
                        const float km = kpm[b*Sq + key] ? -1e30f : 0.0f;
                        sv += (am[(size_t)(qrow + quad*4 + r)*Sq + key] + km) * LOG2E;
                    }
                    macc[su][j][r] += exp2f(sv) * (rl4[r] * 0.0625f);
                }
        }

        __syncthreads();                      // readers of tile h done
        if (h < Hh - 1) {                     // stage tile h+1
            const __hip_bfloat16* kn = Kp + (base + Sq + kc)*Dd;
            uint4 kr0 = *(const uint4*)(kn + (size_t)t*8);
            uint4 kr1 = *(const uint4*)(kn + (size_t)(t + 256)*8);
            *(uint4*)&Ks[off0] = kr0;
            *(uint4*)&Ks[off1] = kr1;
        }
    }

#pragma unroll
    for (int su = 0; su < 2; su++)
#pragma unroll
        for (int j = 0; j < 4; j++)
#pragma unroll
            for (int r = 0; r < 4; r++)
                attn_mean[((size_t)b*Sq + qa + su*16 + quad*4 + r)*Sq + kc + j*16 + lm] =
                    macc[su][j][r];
}

// ---------------- GEMM 2: output projection, bf16 MFMA ----------------
__global__ __launch_bounds__(256) void gemm_out(
    const __hip_bfloat16* __restrict__ A, const __hip_bfloat16* __restrict__ Bw,
    const float* __restrict__ bias, float* __restrict__ outp)
{
    __shared__ __align__(16) __hip_bfloat16 As[128*32];
    __shared__ __align__(16) __hip_bfloat16 Bs[128*32];
    const int t = threadIdx.x;
    const int l = t & 63, lm = l & 15, quad = l >> 4;
    const int w = t >> 6;
    const int mw = (w & 1)*64, nw = (w >> 1)*64;
    const int m0 = blockIdx.y*128, n0 = blockIdx.x*128;

    const int srow = t >> 2;
    const int scol = (t & 3)*8;
    const __hip_bfloat16* ag = A  + (size_t)(m0 + srow)*1024 + scol;
    const __hip_bfloat16* bg = Bw + (size_t)(n0 + srow)*1024 + scol;
    __hip_bfloat16* al = As + t*8;
    __hip_bfloat16* bl = Bs + t*8;

    f32x4 acc[4][4] = {};
    for (int k0 = 0; k0 < 1024; k0 += 32) {
        __syncthreads();
        gld16(ag + k0, al);
        gld16(ag + (size_t)64*1024 + k0, al + 2048);
        gld16(bg + k0, bl);
        gld16(bg + (size_t)64*1024 + k0, bl + 2048);
        __syncthreads();
        bhalf8 af[4], bf[4];
#pragma unroll
        for (int i = 0; i < 4; i++) {
            af[i] = *(const bhalf8*)&As[(mw + i*16 + lm)*32 + quad*8];
            bf[i] = *(const bhalf8*)&Bs[(nw + i*16 + lm)*32 + quad*8];
        }
#pragma unroll
        for (int mf = 0; mf < 4; mf++)
#pragma unroll
            for (int nf = 0; nf < 4; nf++)
                acc[mf][nf] = __builtin_amdgcn_mfma_f32_16x16x32_bf16(af[mf], bf[nf], acc[mf][nf], 0,0,0);
    }
#pragma unroll
    for (int nf = 0; nf < 4; nf++) {
        const int n = n0 + nw + nf*16 + lm;
        const float bz = bias[n];
#pragma unroll
        for (int mf = 0; mf < 4; mf++)
#pragma unroll
            for (int r = 0; r < 4; r++) {
                const int m = m0 + mw + mf*16 + quad*4 + r;
                const int b2 = m >> 11, s2 = m & 2047;
                outp[((size_t)s2*Bb + b2)*Ee + n] = acc[mf][nf][r] + bz;
            }
    }
}

extern "C" void kernel_launch(void* const* d_in, const int* in_sizes, int n_in,
                              void* d_out, int out_size, void* d_ws, size_t ws_size,
                              hipStream_t stream) {
    const float*         x         = (const float*)d_in[0];
    const float*         attn_mask = (const float*)d_in[1];
    const unsigned char* kpm       = (const unsigned char*)d_in[2];
    const float*         qkv_w     = (const float*)d_in[3];
    const float*         qkv_b     = (const float*)d_in[4];
    const float*         out_w     = (const float*)d_in[5];
    const float*         out_b     = (const float*)d_in[6];

    float* outp      = (float*)d_out;
    float* attn_mean = outp + 4194304;          // S*B*E

    __hip_bfloat16* xb  = (__hip_bfloat16*)d_ws;     // 8 MB
    __hip_bfloat16* qwb = xb  + 4194304;             // 6 MB
    __hip_bfloat16* owb = qwb + 3145728;             // 2 MB
    __hip_bfloat16* Qp  = owb + 1048576;             // 8 MB (pre-scaled by QSCALE)
    __hip_bfloat16* Kp  = Qp  + 4194304;             // 8 MB
    __hip_bfloat16* Vt  = Kp  + 4194304;             // 8 MB (transposed [B,H,D,S])
    __hip_bfloat16* wab = Vt  + 4194304;             // 8 MB
    float* rlbuf        = (float*)(wab + 4194304);   // 256 KB
    unsigned int* flag  = (unsigned int*)(rlbuf + 65536);

    hipMemsetAsync(flag, 0, sizeof(unsigned int), stream);
    prep_k<<<12288, 256, 0, stream>>>(x, attn_mask, (const unsigned int*)kpm,
                                      qkv_w, out_w, xb, qwb, owb, flag);
    gemm_qkv<<<dim3(24, 32), 256, 0, stream>>>(xb, qwb, qkv_b, Qp, Kp, Vt);
    attn_mfma<<<dim3(1024), 256, 0, stream>>>(Qp, Kp, Vt, attn_mask, kpm, flag, wab, rlbuf);
    attn_mean_k<<<dim3(1024), 256, 0, stream>>>(Qp, Kp, attn_mask, kpm, flag, rlbuf, attn_mean);
    gemm_out<<<dim3(8, 32), 256, 0, stream>>>(wab, owb, out_b, outp);
}

// Round 6
// 318.560 us; speedup vs baseline: 2.0547x; 1.0715x over previous
//
#include <hip/hip_runtime.h>
#include <hip/hip_bf16.h>

// MHA forward, round 12: conflict-free staging writes via thread->slot swizzle.
// Round-11 counters: attn_mfma's remaining 2.94e7 conflict cycles are ENTIRELY
// the ds_write_b128 staging (tile_off(t) puts lanes 0..7 in the same 16B bank
// quad -> 8-way write serialization; 16 instr x 56 cy = 896/block-kt = exact
// counter match). Fix costs zero instructions: thread t stages global slot
// g = (t&~63)|((t&7)<<3)|((t>>3)&7) so write quad = t&7 (distinct per cycle
// group). Wave footprint/coalescing unchanged. Applied to attn_mfma (K+V) and
// attn_mean_k (K). Everything else identical to round 11 (341 us best).
// S=2048 B=2 E=1024 H=16 D=64. scale folded into Q (exp2).
// ws (48.3 MB): xb | qwb | owb | Qp | Kp | Vt | wab | rl | flag
// d_out: out[S,B,E] fp32 (4194304) then attn_mean[B,S,S] fp32 (8388608).

#define Sq 2048
#define Bb 2
#define Ee 1024
#define Hh 16
#define Dd 64
#define LOG2E 1.4426950408889634f
#define QSCALE 0.18033688011112042f   // 0.125 * log2(e)

typedef __attribute__((ext_vector_type(8))) short bhalf8;   // 8 bf16 (4 VGPRs)
typedef __attribute__((ext_vector_type(4))) float f32x4;

__device__ __forceinline__ void gld16(const __hip_bfloat16* g, __hip_bfloat16* l) {
    __builtin_amdgcn_global_load_lds(
        (const __attribute__((address_space(1))) unsigned int*)g,
        (__attribute__((address_space(3))) unsigned int*)l, 16, 0, 0);
}

__device__ __forceinline__ int pkbf(float a, float b) {
    union { __hip_bfloat16 h[2]; int i; } u;
    u.h[0] = __float2bfloat16(a);
    u.h[1] = __float2bfloat16(b);
    return u.i;
}

// slot s (0..511, 16B chunks of a 64x64 bf16 tile, global-linear) -> swizzled
// frag-major LDS elem offset [f|ks][j|nd][quad][lm][8]
__device__ __forceinline__ int tile_off(int s) {
    return ((s >> 2) & 1) * 2048 + (s >> 7) * 512 + (s & 3) * 128 + ((s >> 3) & 15) * 8;
}

// thread t -> staged global slot g: swap lo3<->mid3 bits within the 64-slot
// window so the tile_off(g) write has bank-quad (g>>3)&7 == t&7 (conflict-free
// 8-lane cycle groups). Bijective per window => wave coalescing unchanged.
__device__ __forceinline__ int swz(int t) {
    return (t & ~63) | ((t & 7) << 3) | ((t >> 3) & 7);
}

// K row permutation: LDS tile row position p holds global key kperm(p).
// p = j*16 + quad*4 + r  ->  key = 32*(j&1) + 8*quad + 4*(j>>1) + r
// so that the QK^T C-registers directly form the PV B-fragment (no shuffles).
__device__ __forceinline__ int kperm(int p) {
    return (p & 3) | (((p >> 5) & 1) << 2) | ((p & 12) << 1) | (((p >> 4) & 1) << 5);
}

// ---------------- fused prep: mask scan + fp32->bf16 conversions ----------------
__global__ __launch_bounds__(256) void prep_k(
    const float* __restrict__ x, const float* __restrict__ am,
    const unsigned int* __restrict__ kpm32,
    const float* __restrict__ qkv_w, const float* __restrict__ out_w,
    __hip_bfloat16* __restrict__ xb, __hip_bfloat16* __restrict__ qwb,
    __hip_bfloat16* __restrict__ owb, unsigned int* __restrict__ flag)
{
    const long i = (long)blockIdx.x*256 + threadIdx.x;
    if (i < 1048576) {                       // mask scan (am 1M float4, kpm 1024 u32)
        float4 v = ((const float4*)am)[i];
        bool nz = (v.x != 0.f) | (v.y != 0.f) | (v.z != 0.f) | (v.w != 0.f);
        if (i < 1024) nz |= (kpm32[i] != 0u);
        if (__ballot(nz)) { if ((threadIdx.x & 63) == 0) atomicOr(flag, 1u); }
    } else if (i < 2097152) {                // x conv with [S,B,E]->[B*S][E]
        const long j = i - 1048576;
        const int m = (int)(j >> 8), e4 = (int)(j & 255);
        const int b = m >> 11, s = m & 2047;
        float4 v = ((const float4*)x)[(size_t)(s*Bb + b)*256 + e4];
        union { __hip_bfloat16 h[4]; uint2 u; } o;
        o.h[0]=__float2bfloat16(v.x); o.h[1]=__float2bfloat16(v.y);
        o.h[2]=__float2bfloat16(v.z); o.h[3]=__float2bfloat16(v.w);
        ((uint2*)xb)[(size_t)m*256 + e4] = o.u;
    } else if (i < 2883584) {                // qkv_w conv (786432 float4)
        const long j = i - 2097152;
        float4 v = ((const float4*)qkv_w)[j];
        union { __hip_bfloat16 h[4]; uint2 u; } o;
        o.h[0]=__float2bfloat16(v.x); o.h[1]=__float2bfloat16(v.y);
        o.h[2]=__float2bfloat16(v.z); o.h[3]=__float2bfloat16(v.w);
        ((uint2*)qwb)[j] = o.u;
    } else if (i < 3145728) {                // out_w conv (262144 float4)
        const long j = i - 2883584;
        float4 v = ((const float4*)out_w)[j];
        union { __hip_bfloat16 h[4]; uint2 u; } o;
        o.h[0]=__float2bfloat16(v.x); o.h[1]=__float2bfloat16(v.y);
        o.h[2]=__float2bfloat16(v.z); o.h[3]=__float2bfloat16(v.w);
        ((uint2*)owb)[j] = o.u;
    }
}

// ---------------- GEMM 1: QKV projection, bf16 MFMA, scatter epilogue ----------------
// Q stored pre-scaled by QSCALE.
__global__ __launch_bounds__(256) void gemm_qkv(
    const __hip_bfloat16* __restrict__ A, const __hip_bfloat16* __restrict__ Bw,
    const float* __restrict__ bias,
    __hip_bfloat16* __restrict__ Qp, __hip_bfloat16* __restrict__ Kp,
    __hip_bfloat16* __restrict__ Vt)
{
    __shared__ __align__(16) __hip_bfloat16 As[128*32];
    __shared__ __align__(16) __hip_bfloat16 Bs[128*32];
    const int t = threadIdx.x;
    const int l = t & 63, lm = l & 15, quad = l >> 4;
    const int w = t >> 6;
    const int mw = (w & 1)*64, nw = (w >> 1)*64;
    const int m0 = blockIdx.y*128, n0 = blockIdx.x*128;

    const int srow = t >> 2;              // 0..63
    const int scol = (t & 3)*8;
    const __hip_bfloat16* ag = A  + (size_t)(m0 + srow)*1024 + scol;
    const __hip_bfloat16* bg = Bw + (size_t)(n0 + srow)*1024 + scol;
    __hip_bfloat16* al = As + t*8;
    __hip_bfloat16* bl = Bs + t*8;

    f32x4 acc[4][4] = {};
    for (int k0 = 0; k0 < 1024; k0 += 32) {
        __syncthreads();
        gld16(ag + k0, al);
        gld16(ag + (size_t)64*1024 + k0, al + 2048);
        gld16(bg + k0, bl);
        gld16(bg + (size_t)64*1024 + k0, bl + 2048);
        __syncthreads();
        bhalf8 af[4], bf[4];
#pragma unroll
        for (int i = 0; i < 4; i++) {
            af[i] = *(const bhalf8*)&As[(mw + i*16 + lm)*32 + quad*8];
            bf[i] = *(const bhalf8*)&Bs[(nw + i*16 + lm)*32 + quad*8];
        }
#pragma unroll
        for (int mf = 0; mf < 4; mf++)
#pragma unroll
            for (int nf = 0; nf < 4; nf++)
                acc[mf][nf] = __builtin_amdgcn_mfma_f32_16x16x32_bf16(af[mf], bf[nf], acc[mf][nf], 0,0,0);
    }
#pragma unroll
    for (int nf = 0; nf < 4; nf++) {
        const int n = n0 + nw + nf*16 + lm;
        const float bz = bias[n];
        const int which = n >> 10, hh = (n >> 6) & 15, dd = n & 63;
#pragma unroll
        for (int mf = 0; mf < 4; mf++)
#pragma unroll
            for (int r = 0; r < 4; r++) {
                const int m = m0 + mw + mf*16 + quad*4 + r;
                const int b2 = m >> 11, s2 = m & 2047;
                const float vf = acc[mf][nf][r] + bz;
                if (which == 0)
                    Qp[((size_t)(b2*Hh + hh)*Sq + s2)*Dd + dd] = __float2bfloat16(vf * QSCALE);
                else if (which == 1)
                    Kp[((size_t)(b2*Hh + hh)*Sq + s2)*Dd + dd] = __float2bfloat16(vf);
                else
                    Vt[((size_t)(b2*Hh + hh)*Dd + dd)*Sq + s2] = __float2bfloat16(vf);
            }
    }
}

// ---------------- Attention core: LDS-staged tiles, XCD-pinned, shuffle-free PV ----------------
// blk = xcd + 8*qt + 256*grp ; bh = grp*8 + xcd. Block = 4 waves x 16 q rows.
// Per kt: K tile (8KB) + V^T tile (8KB) staged into swizzled frag-major LDS.
// K rows permuted at the GLOBAL source (kperm) so QK^T C-regs form the PV
// B-fragment; thread->slot swz makes the staging writes bank-conflict-free.
__global__ __launch_bounds__(256, 4) void attn_mfma(
    const __hip_bfloat16* __restrict__ Qp, const __hip_bfloat16* __restrict__ Kp,
    const __hip_bfloat16* __restrict__ Vt,
    const float* __restrict__ am, const unsigned char* __restrict__ kpm,
    const unsigned int* __restrict__ flag,
    __hip_bfloat16* __restrict__ wa, float* __restrict__ rlbuf)
{
    __shared__ __align__(16) __hip_bfloat16 Ks[4096];
    __shared__ __align__(16) __hip_bfloat16 Vs[4096];
    const int t = threadIdx.x;
    const int w = t >> 6, l = t & 63, lm = l & 15, quad = l >> 4;
    const int blk = blockIdx.x;
    const int xcd = blk & 7;
    const int qt  = (blk >> 3) & 31;
    const int grp = blk >> 8;                  // 0..3
    const int bh  = grp*8 + xcd;
    const int b   = bh >> 4, h = bh & 15;
    const int q   = qt*64 + w*16 + lm;
    const bool masked = (flag[0] != 0u);

    const __hip_bfloat16* qbase = Qp + (size_t)bh*Sq*Dd;
    const __hip_bfloat16* kbase = Kp + (size_t)bh*Sq*Dd;
    const __hip_bfloat16* vbase = Vt + (size_t)bh*Dd*Sq;

    // Q as B-operand (pre-scaled), one-time strided load
    bhalf8 bq[2];
    bq[0] = *(const bhalf8*)(qbase + (size_t)q*Dd + quad*8);
    bq[1] = *(const bhalf8*)(qbase + (size_t)q*Dd + quad*8 + 32);

    f32x4 o[4] = {};
    float lsum = 0.f;

    // staged slots for this thread (swizzled: conflict-free tile_off writes)
    const int g0 = swz(t), g1 = g0 + 256;
    const int off0 = tile_off(g0), off1 = tile_off(g1);
    // permuted global K rows feeding those slots
    const int krow0 = kperm(g0 >> 3);
    const int krow1 = kperm(g1 >> 3);
    const int kcol  = (g0 & 7)*8;
    const int vrow0 = g0 >> 3, vrow1 = g1 >> 3;

    // preload tile 0 staging regs
    uint4 kreg0 = *(const uint4*)(kbase + (size_t)krow0*Dd + kcol);
    uint4 kreg1 = *(const uint4*)(kbase + (size_t)krow1*Dd + kcol);
    uint4 vreg0 = *(const uint4*)(vbase + (size_t)vrow0*Sq + kcol);
    uint4 vreg1 = *(const uint4*)(vbase + (size_t)vrow1*Sq + kcol);

    for (int kt = 0; kt < 32; kt++) {
        __syncthreads();                       // previous tile's readers done
        *(uint4*)&Ks[off0] = kreg0;
        *(uint4*)&Ks[off1] = kreg1;
        *(uint4*)&Vs[off0] = vreg0;
        *(uint4*)&Vs[off1] = vreg1;
        if (kt < 31) {                         // prefetch tile kt+1
            const int kn = (kt + 1)*64;
            kreg0 = *(const uint4*)(kbase + (size_t)(kn + krow0)*Dd + kcol);
            kreg1 = *(const uint4*)(kbase + (size_t)(kn + krow1)*Dd + kcol);
            vreg0 = *(const uint4*)(vbase + (size_t)vrow0*Sq + kn + kcol);
            vreg1 = *(const uint4*)(vbase + (size_t)vrow1*Sq + kn + kcol);
        }
        __syncthreads();                       // tile kt visible

        const int k0 = kt*64;
        // S^T = K · Q^T  (K rows permuted: row p holds key kperm(p))
        f32x4 s[4] = {};
#pragma unroll
        for (int f = 0; f < 2; f++) {
            bhalf8 ak[4];
#pragma unroll
            for (int j = 0; j < 4; j++)
                ak[j] = *(const bhalf8*)&Ks[f*2048 + j*512 + l*8];
#pragma unroll
            for (int j = 0; j < 4; j++)
                s[j] = __builtin_amdgcn_mfma_f32_16x16x32_bf16(ak[j], bq[f], s[j], 0,0,0);
        }

        // exp2 + pack; s[j][r] is key k0 + 32*(j&1) + 8*quad + 4*(j>>1) + r
        int pk[4][2];
#pragma unroll
        for (int j = 0; j < 4; j++) {
            float p[4];
#pragma unroll
            for (int r = 0; r < 4; r++) {
                float sv = s[j][r];
                if (masked) {
                    const int key = k0 + 32*(j & 1) + 8*quad + 4*(j >> 1) + r;
                    const float km = kpm[b*Sq + key] ? -1e30f : 0.0f;
                    sv += (am[(size_t)q*Sq + key] + km) * LOG2E;
                }
                p[r] = exp2f(sv);
            }
            lsum += (p[0]+p[1]) + (p[2]+p[3]);
            pk[j][0] = pkbf(p[0], p[1]);
            pk[j][1] = pkbf(p[2], p[3]);
        }

        // PV: O^T += V^T · P^T — P^T B-frag is lane-local by construction:
        // lane needs keys ks*32 + quad*8 + e  ==  {pk[ks], pk[ks+2]}
#pragma unroll
        for (int ks = 0; ks < 2; ks++) {
            union { int i[4]; bhalf8 v; } bp;
            bp.i[0] = pk[ks][0];
            bp.i[1] = pk[ks][1];
            bp.i[2] = pk[ks + 2][0];
            bp.i[3] = pk[ks + 2][1];
            bhalf8 av[4];
#pragma unroll
            for (int nd = 0; nd < 4; nd++)
                av[nd] = *(const bhalf8*)&Vs[ks*2048 + nd*512 + l*8];
#pragma unroll
            for (int nd = 0; nd < 4; nd++)
                o[nd] = __builtin_amdgcn_mfma_f32_16x16x32_bf16(av[nd], bp.v, o[nd], 0,0,0);
        }
    }

    lsum += __shfl_xor(lsum, 16, 64);
    lsum += __shfl_xor(lsum, 32, 64);
    const float rl = 1.0f / lsum;
    if (quad == 0) rlbuf[(size_t)bh*Sq + q] = rl;

#pragma unroll
    for (int nd = 0; nd < 4; nd++) {
        union { __hip_bfloat16 hx[4]; uint2 u; } ou;
#pragma unroll
        for (int r = 0; r < 4; r++) ou.hx[r] = __float2bfloat16(o[nd][r] * rl);
        *(uint2*)(wa + ((size_t)b*Sq + q)*Ee + h*Dd + nd*16 + quad*4) = ou.u;
    }
}

// ---------------- attn_mean: 128q x 64k, K in LDS (swizzled stage), Q direct ----------------
// 1024 blocks x 256 threads (4 waves); wave w owns q rows [q0 + w*32, +32).
// 1D grid XCD-pinned: blk&7 -> q0 low bits so the 32 kc-blocks sharing one Q
// slice run consecutively on one XCD. K tile staged via contiguous uint4 +
// swz thread->slot (conflict-free tile_off writes). Q A-frags direct global.
__global__ __launch_bounds__(256) void attn_mean_k(
    const __hip_bfloat16* __restrict__ Qp, const __hip_bfloat16* __restrict__ Kp,
    const float* __restrict__ am, const unsigned char* __restrict__ kpm,
    const unsigned int* __restrict__ flag,
    const float* __restrict__ rlbuf, float* __restrict__ attn_mean)
{
    __shared__ __align__(16) __hip_bfloat16 Ks[4096];   // 64 keys x 64 d, frag-major
    const int t = threadIdx.x;
    const int w = t >> 6, l = t & 63, lm = l & 15, quad = l >> 4;
    const int blk = blockIdx.x;
    const int q0idx = (blk & 7) | (((blk >> 8) & 1) << 3);   // 0..15
    const int kc    = ((blk >> 3) & 31) * 64;
    const int b     = (blk >> 9) & 1;
    const int q0    = q0idx * 128;
    const bool masked = (flag[0] != 0u);

    const int g0 = swz(t), g1 = g0 + 256;
    const int off0 = tile_off(g0), off1 = tile_off(g1);
    const int qa = q0 + w*32;                 // wave's 32 q rows

    float macc[2][4][4] = {};

    // preload h=0 K staging (coalesced within the 64-slot window)
    {
        const __hip_bfloat16* kg = Kp + ((size_t)(b*Hh)*Sq + kc)*Dd;
        uint4 kr0 = *(const uint4*)(kg + (size_t)g0*8);
        uint4 kr1 = *(const uint4*)(kg + (size_t)g1*8);
        *(uint4*)&Ks[off0] = kr0;
        *(uint4*)&Ks[off1] = kr1;
    }

    for (int h = 0; h < Hh; h++) {
        __syncthreads();                      // K tile for h visible
        const size_t base = (size_t)(b*Hh + h)*Sq;

#pragma unroll
        for (int su = 0; su < 2; su++) {
            const int qrow = qa + su*16;
            const __hip_bfloat16* qg = Qp + (base + qrow + lm)*Dd + quad*8;
            f32x4 s[4] = {};
#pragma unroll
            for (int f = 0; f < 2; f++) {
                bhalf8 aq = *(const bhalf8*)(qg + f*32);
#pragma unroll
                for (int j = 0; j < 4; j++) {
                    bhalf8 bk = *(const bhalf8*)&Ks[f*2048 + j*512 + l*8];
                    s[j] = __builtin_amdgcn_mfma_f32_16x16x32_bf16(aq, bk, s[j], 0,0,0);
                }
            }
            const f32x4 rl4 = *(const f32x4*)(rlbuf + base + qrow + quad*4);
#pragma unroll
            for (int j = 0; j < 4; j++)
#pragma unroll
                for (int r = 0; r < 4; r++) {
                    float sv = s[j][r];
                    if (masked) {
                        const int key = kc + j*16 + lm;
                        const float km = kpm[b*Sq + key] ? -1e30f : 0.0f;
                        sv += (am[(size_t)(qrow + quad*4 + r)*Sq + key] + km) * LOG2E;
                    }
                    macc[su][j][r] += exp2f(sv) * (rl4[r] * 0.0625f);
                }
        }

        __syncthreads();                      // readers of tile h done
        if (h < Hh - 1) {                     // stage tile h+1
            const __hip_bfloat16* kn = Kp + (base + Sq + kc)*Dd;
            uint4 kr0 = *(const uint4*)(kn + (size_t)g0*8);
            uint4 kr1 = *(const uint4*)(kn + (size_t)g1*8);
            *(uint4*)&Ks[off0] = kr0;
            *(uint4*)&Ks[off1] = kr1;
        }
    }

#pragma unroll
    for (int su = 0; su < 2; su++)
#pragma unroll
        for (int j = 0; j < 4; j++)
#pragma unroll
            for (int r = 0; r < 4; r++)
                attn_mean[((size_t)b*Sq + qa + su*16 + quad*4 + r)*Sq + kc + j*16 + lm] =
                    macc[su][j][r];
}

// ---------------- GEMM 2: output projection, bf16 MFMA ----------------
__global__ __launch_bounds__(256) void gemm_out(
    const __hip_bfloat16* __restrict__ A, const __hip_bfloat16* __restrict__ Bw,
    const float* __restrict__ bias, float* __restrict__ outp)
{
    __shared__ __align__(16) __hip_bfloat16 As[128*32];
    __shared__ __align__(16) __hip_bfloat16 Bs[128*32];
    const int t = threadIdx.x;
    const int l = t & 63, lm = l & 15, quad = l >> 4;
    const int w = t >> 6;
    const int mw = (w & 1)*64, nw = (w >> 1)*64;
    const int m0 = blockIdx.y*128, n0 = blockIdx.x*128;

    const int srow = t >> 2;
    const int scol = (t & 3)*8;
    const __hip_bfloat16* ag = A  + (size_t)(m0 + srow)*1024 + scol;
    const __hip_bfloat16* bg = Bw + (size_t)(n0 + srow)*1024 + scol;
    __hip_bfloat16* al = As + t*8;
    __hip_bfloat16* bl = Bs + t*8;

    f32x4 acc[4][4] = {};
    for (int k0 = 0; k0 < 1024; k0 += 32) {
        __syncthreads();
        gld16(ag + k0, al);
        gld16(ag + (size_t)64*1024 + k0, al + 2048);
        gld16(bg + k0, bl);
        gld16(bg + (size_t)64*1024 + k0, bl + 2048);
        __syncthreads();
        bhalf8 af[4], bf[4];
#pragma unroll
        for (int i = 0; i < 4; i++) {
            af[i] = *(const bhalf8*)&As[(mw + i*16 + lm)*32 + quad*8];
            bf[i] = *(const bhalf8*)&Bs[(nw + i*16 + lm)*32 + quad*8];
        }
#pragma unroll
        for (int mf = 0; mf < 4; mf++)
#pragma unroll
            for (int nf = 0; nf < 4; nf++)
                acc[mf][nf] = __builtin_amdgcn_mfma_f32_16x16x32_bf16(af[mf], bf[nf], acc[mf][nf], 0,0,0);
    }
#pragma unroll
    for (int nf = 0; nf < 4; nf++) {
        const int n = n0 + nw + nf*16 + lm;
        const float bz = bias[n];
#pragma unroll
        for (int mf = 0; mf < 4; mf++)
#pragma unroll
            for (int r = 0; r < 4; r++) {
                const int m = m0 + mw + mf*16 + quad*4 + r;
                const int b2 = m >> 11, s2 = m & 2047;
                outp[((size_t)s2*Bb + b2)*Ee + n] = acc[mf][nf][r] + bz;
            }
    }
}

extern "C" void kernel_launch(void* const* d_in, const int* in_sizes, int n_in,
                              void* d_out, int out_size, void* d_ws, size_t ws_size,
                              hipStream_t stream) {
    const float*         x         = (const float*)d_in[0];
    const float*         attn_mask = (const float*)d_in[1];
    const unsigned char* kpm       = (const unsigned char*)d_in[2];
    const float*         qkv_w     = (const float*)d_in[3];
    const float*         qkv_b     = (const float*)d_in[4];
    const float*         out_w     = (const float*)d_in[5];
    const float*         out_b     = (const float*)d_in[6];

    float* outp      = (float*)d_out;
    float* attn_mean = outp + 4194304;          // S*B*E

    __hip_bfloat16* xb  = (__hip_bfloat16*)d_ws;     // 8 MB
    __hip_bfloat16* qwb = xb  + 4194304;             // 6 MB
    __hip_bfloat16* owb = qwb + 3145728;             // 2 MB
    __hip_bfloat16* Qp  = owb + 1048576;             // 8 MB (pre-scaled by QSCALE)
    __hip_bfloat16* Kp  = Qp  + 4194304;             // 8 MB
    __hip_bfloat16* Vt  = Kp  + 4194304;             // 8 MB (transposed [B,H,D,S])
    __hip_bfloat16* wab = Vt  + 4194304;             // 8 MB
    float* rlbuf        = (float*)(wab + 4194304);   // 256 KB
    unsigned int* flag  = (unsigned int*)(rlbuf + 65536);

    hipMemsetAsync(flag, 0, sizeof(unsigned int), stream);
    prep_k<<<12288, 256, 0, stream>>>(x, attn_mask, (const unsigned int*)kpm,
                                      qkv_w, out_w, xb, qwb, owb, flag);
    gemm_qkv<<<dim3(24, 32), 256, 0, stream>>>(xb, qwb, qkv_b, Qp, Kp, Vt);
    attn_mfma<<<dim3(1024), 256, 0, stream>>>(Qp, Kp, Vt, attn_mask, kpm, flag, wab, rlbuf);
    attn_mean_k<<<dim3(1024), 256, 0, stream>>>(Qp, Kp, attn_mask, kpm, flag, rlbuf, attn_mean);
    gemm_out<<<dim3(8, 32), 256, 0, stream>>>(wab, owb, out_b, outp);
}

// Round 7
// 307.952 us; speedup vs baseline: 2.1255x; 1.0344x over previous
//
#include <hip/hip_runtime.h>
#include <hip/hip_bf16.h>

// MHA forward, round 13: prefetch-early double-buffered attn_mean staging.
// Round-12 counters: attn_mean_k spill-free (WRITE=output), conflict-free,
// near-ideal traffic, but latency-bound (VALU 43.8%, Mfma 7.8%, HBM 10%):
// its per-h schedule exposed full global-load latency (loads issued right
// before their ds_write consumers) + 2 barriers/h. Round 13 gives it the
// attn_mfma-proven schedule: Ks[2] double buffer, stage writes + next-next
// loads issued at top of iteration (hidden under compute), 1 barrier/h.
// Also: rlbuf now stores rl/16 (folded in attn_mfma epilogue).
// S=2048 B=2 E=1024 H=16 D=64. scale folded into Q (exp2).
// ws (48.3 MB): xb | qwb | owb | Qp | Kp | Vt | wab | rl | flag
// d_out: out[S,B,E] fp32 (4194304) then attn_mean[B,S,S] fp32 (8388608).

#define Sq 2048
#define Bb 2
#define Ee 1024
#define Hh 16
#define Dd 64
#define LOG2E 1.4426950408889634f
#define QSCALE 0.18033688011112042f   // 0.125 * log2(e)

typedef __attribute__((ext_vector_type(8))) short bhalf8;   // 8 bf16 (4 VGPRs)
typedef __attribute__((ext_vector_type(4))) float f32x4;

__device__ __forceinline__ void gld16(const __hip_bfloat16* g, __hip_bfloat16* l) {
    __builtin_amdgcn_global_load_lds(
        (const __attribute__((address_space(1))) unsigned int*)g,
        (__attribute__((address_space(3))) unsigned int*)l, 16, 0, 0);
}

__device__ __forceinline__ int pkbf(float a, float b) {
    union { __hip_bfloat16 h[2]; int i; } u;
    u.h[0] = __float2bfloat16(a);
    u.h[1] = __float2bfloat16(b);
    return u.i;
}

// slot s (0..511, 16B chunks of a 64x64 bf16 tile, global-linear) -> swizzled
// frag-major LDS elem offset [f|ks][j|nd][quad][lm][8]
__device__ __forceinline__ int tile_off(int s) {
    return ((s >> 2) & 1) * 2048 + (s >> 7) * 512 + (s & 3) * 128 + ((s >> 3) & 15) * 8;
}

// thread t -> staged global slot g: swap lo3<->mid3 bits within the 64-slot
// window so the tile_off(g) write has bank-quad (g>>3)&7 == t&7 (conflict-free
// 8-lane cycle groups). Bijective per window => wave coalescing unchanged.
__device__ __forceinline__ int swz(int t) {
    return (t & ~63) | ((t & 7) << 3) | ((t >> 3) & 7);
}

// K row permutation: LDS tile row position p holds global key kperm(p).
// p = j*16 + quad*4 + r  ->  key = 32*(j&1) + 8*quad + 4*(j>>1) + r
// so that the QK^T C-registers directly form the PV B-fragment (no shuffles).
__device__ __forceinline__ int kperm(int p) {
    return (p & 3) | (((p >> 5) & 1) << 2) | ((p & 12) << 1) | (((p >> 4) & 1) << 5);
}

// ---------------- fused prep: mask scan + fp32->bf16 conversions ----------------
__global__ __launch_bounds__(256) void prep_k(
    const float* __restrict__ x, const float* __restrict__ am,
    const unsigned int* __restrict__ kpm32,
    const float* __restrict__ qkv_w, const float* __restrict__ out_w,
    __hip_bfloat16* __restrict__ xb, __hip_bfloat16* __restrict__ qwb,
    __hip_bfloat16* __restrict__ owb, unsigned int* __restrict__ flag)
{
    const long i = (long)blockIdx.x*256 + threadIdx.x;
    if (i < 1048576) {                       // mask scan (am 1M float4, kpm 1024 u32)
        float4 v = ((const float4*)am)[i];
        bool nz = (v.x != 0.f) | (v.y != 0.f) | (v.z != 0.f) | (v.w != 0.f);
        if (i < 1024) nz |= (kpm32[i] != 0u);
        if (__ballot(nz)) { if ((threadIdx.x & 63) == 0) atomicOr(flag, 1u); }
    } else if (i < 2097152) {                // x conv with [S,B,E]->[B*S][E]
        const long j = i - 1048576;
        const int m = (int)(j >> 8), e4 = (int)(j & 255);
        const int b = m >> 11, s = m & 2047;
        float4 v = ((const float4*)x)[(size_t)(s*Bb + b)*256 + e4];
        union { __hip_bfloat16 h[4]; uint2 u; } o;
        o.h[0]=__float2bfloat16(v.x); o.h[1]=__float2bfloat16(v.y);
        o.h[2]=__float2bfloat16(v.z); o.h[3]=__float2bfloat16(v.w);
        ((uint2*)xb)[(size_t)m*256 + e4] = o.u;
    } else if (i < 2883584) {                // qkv_w conv (786432 float4)
        const long j = i - 2097152;
        float4 v = ((const float4*)qkv_w)[j];
        union { __hip_bfloat16 h[4]; uint2 u; } o;
        o.h[0]=__float2bfloat16(v.x); o.h[1]=__float2bfloat16(v.y);
        o.h[2]=__float2bfloat16(v.z); o.h[3]=__float2bfloat16(v.w);
        ((uint2*)qwb)[j] = o.u;
    } else if (i < 3145728) {                // out_w conv (262144 float4)
        const long j = i - 2883584;
        float4 v = ((const float4*)out_w)[j];
        union { __hip_bfloat16 h[4]; uint2 u; } o;
        o.h[0]=__float2bfloat16(v.x); o.h[1]=__float2bfloat16(v.y);
        o.h[2]=__float2bfloat16(v.z); o.h[3]=__float2bfloat16(v.w);
        ((uint2*)owb)[j] = o.u;
    }
}

// ---------------- GEMM 1: QKV projection, bf16 MFMA, scatter epilogue ----------------
// Q stored pre-scaled by QSCALE.
__global__ __launch_bounds__(256) void gemm_qkv(
    const __hip_bfloat16* __restrict__ A, const __hip_bfloat16* __restrict__ Bw,
    const float* __restrict__ bias,
    __hip_bfloat16* __restrict__ Qp, __hip_bfloat16* __restrict__ Kp,
    __hip_bfloat16* __restrict__ Vt)
{
    __shared__ __align__(16) __hip_bfloat16 As[128*32];
    __shared__ __align__(16) __hip_bfloat16 Bs[128*32];
    const int t = threadIdx.x;
    const int l = t & 63, lm = l & 15, quad = l >> 4;
    const int w = t >> 6;
    const int mw = (w & 1)*64, nw = (w >> 1)*64;
    const int m0 = blockIdx.y*128, n0 = blockIdx.x*128;

    const int srow = t >> 2;              // 0..63
    const int scol = (t & 3)*8;
    const __hip_bfloat16* ag = A  + (size_t)(m0 + srow)*1024 + scol;
    const __hip_bfloat16* bg = Bw + (size_t)(n0 + srow)*1024 + scol;
    __hip_bfloat16* al = As + t*8;
    __hip_bfloat16* bl = Bs + t*8;

    f32x4 acc[4][4] = {};
    for (int k0 = 0; k0 < 1024; k0 += 32) {
        __syncthreads();
        gld16(ag + k0, al);
        gld16(ag + (size_t)64*1024 + k0, al + 2048);
        gld16(bg + k0, bl);
        gld16(bg + (size_t)64*1024 + k0, bl + 2048);
        __syncthreads();
        bhalf8 af[4], bf[4];
#pragma unroll
        for (int i = 0; i < 4; i++) {
            af[i] = *(const bhalf8*)&As[(mw + i*16 + lm)*32 + quad*8];
            bf[i] = *(const bhalf8*)&Bs[(nw + i*16 + lm)*32 + quad*8];
        }
#pragma unroll
        for (int mf = 0; mf < 4; mf++)
#pragma unroll
            for (int nf = 0; nf < 4; nf++)
                acc[mf][nf] = __builtin_amdgcn_mfma_f32_16x16x32_bf16(af[mf], bf[nf], acc[mf][nf], 0,0,0);
    }
#pragma unroll
    for (int nf = 0; nf < 4; nf++) {
        const int n = n0 + nw + nf*16 + lm;
        const float bz = bias[n];
        const int which = n >> 10, hh = (n >> 6) & 15, dd = n & 63;
#pragma unroll
        for (int mf = 0; mf < 4; mf++)
#pragma unroll
            for (int r = 0; r < 4; r++) {
                const int m = m0 + mw + mf*16 + quad*4 + r;
                const int b2 = m >> 11, s2 = m & 2047;
                const float vf = acc[mf][nf][r] + bz;
                if (which == 0)
                    Qp[((size_t)(b2*Hh + hh)*Sq + s2)*Dd + dd] = __float2bfloat16(vf * QSCALE);
                else if (which == 1)
                    Kp[((size_t)(b2*Hh + hh)*Sq + s2)*Dd + dd] = __float2bfloat16(vf);
                else
                    Vt[((size_t)(b2*Hh + hh)*Dd + dd)*Sq + s2] = __float2bfloat16(vf);
            }
    }
}

// ---------------- Attention core: LDS-staged tiles, XCD-pinned, shuffle-free PV ----------------
// blk = xcd + 8*qt + 256*grp ; bh = grp*8 + xcd. Block = 4 waves x 16 q rows.
// Per kt: K tile (8KB) + V^T tile (8KB) staged into swizzled frag-major LDS.
// K rows permuted at the GLOBAL source (kperm) so QK^T C-regs form the PV
// B-fragment; thread->slot swz makes the staging writes bank-conflict-free.
__global__ __launch_bounds__(256, 4) void attn_mfma(
    const __hip_bfloat16* __restrict__ Qp, const __hip_bfloat16* __restrict__ Kp,
    const __hip_bfloat16* __restrict__ Vt,
    const float* __restrict__ am, const unsigned char* __restrict__ kpm,
    const unsigned int* __restrict__ flag,
    __hip_bfloat16* __restrict__ wa, float* __restrict__ rlbuf)
{
    __shared__ __align__(16) __hip_bfloat16 Ks[4096];
    __shared__ __align__(16) __hip_bfloat16 Vs[4096];
    const int t = threadIdx.x;
    const int w = t >> 6, l = t & 63, lm = l & 15, quad = l >> 4;
    const int blk = blockIdx.x;
    const int xcd = blk & 7;
    const int qt  = (blk >> 3) & 31;
    const int grp = blk >> 8;                  // 0..3
    const int bh  = grp*8 + xcd;
    const int b   = bh >> 4, h = bh & 15;
    const int q   = qt*64 + w*16 + lm;
    const bool masked = (flag[0] != 0u);

    const __hip_bfloat16* qbase = Qp + (size_t)bh*Sq*Dd;
    const __hip_bfloat16* kbase = Kp + (size_t)bh*Sq*Dd;
    const __hip_bfloat16* vbase = Vt + (size_t)bh*Dd*Sq;

    // Q as B-operand (pre-scaled), one-time strided load
    bhalf8 bq[2];
    bq[0] = *(const bhalf8*)(qbase + (size_t)q*Dd + quad*8);
    bq[1] = *(const bhalf8*)(qbase + (size_t)q*Dd + quad*8 + 32);

    f32x4 o[4] = {};
    float lsum = 0.f;

    // staged slots for this thread (swizzled: conflict-free tile_off writes)
    const int g0 = swz(t), g1 = g0 + 256;
    const int off0 = tile_off(g0), off1 = tile_off(g1);
    // permuted global K rows feeding those slots
    const int krow0 = kperm(g0 >> 3);
    const int krow1 = kperm(g1 >> 3);
    const int kcol  = (g0 & 7)*8;
    const int vrow0 = g0 >> 3, vrow1 = g1 >> 3;

    // preload tile 0 staging regs
    uint4 kreg0 = *(const uint4*)(kbase + (size_t)krow0*Dd + kcol);
    uint4 kreg1 = *(const uint4*)(kbase + (size_t)krow1*Dd + kcol);
    uint4 vreg0 = *(const uint4*)(vbase + (size_t)vrow0*Sq + kcol);
    uint4 vreg1 = *(const uint4*)(vbase + (size_t)vrow1*Sq + kcol);

    for (int kt = 0; kt < 32; kt++) {
        __syncthreads();                       // previous tile's readers done
        *(uint4*)&Ks[off0] = kreg0;
        *(uint4*)&Ks[off1] = kreg1;
        *(uint4*)&Vs[off0] = vreg0;
        *(uint4*)&Vs[off1] = vreg1;
        if (kt < 31) {                         // prefetch tile kt+1
            const int kn = (kt + 1)*64;
            kreg0 = *(const uint4*)(kbase + (size_t)(kn + krow0)*Dd + kcol);
            kreg1 = *(const uint4*)(kbase + (size_t)(kn + krow1)*Dd + kcol);
            vreg0 = *(const uint4*)(vbase + (size_t)vrow0*Sq + kn + kcol);
            vreg1 = *(const uint4*)(vbase + (size_t)vrow1*Sq + kn + kcol);
        }
        __syncthreads();                       // tile kt visible

        const int k0 = kt*64;
        // S^T = K · Q^T  (K rows permuted: row p holds key kperm(p))
        f32x4 s[4] = {};
#pragma unroll
        for (int f = 0; f < 2; f++) {
            bhalf8 ak[4];
#pragma unroll
            for (int j = 0; j < 4; j++)
                ak[j] = *(const bhalf8*)&Ks[f*2048 + j*512 + l*8];
#pragma unroll
            for (int j = 0; j < 4; j++)
                s[j] = __builtin_amdgcn_mfma_f32_16x16x32_bf16(ak[j], bq[f], s[j], 0,0,0);
        }

        // exp2 + pack; s[j][r] is key k0 + 32*(j&1) + 8*quad + 4*(j>>1) + r
        int pk[4][2];
#pragma unroll
        for (int j = 0; j < 4; j++) {
            float p[4];
#pragma unroll
            for (int r = 0; r < 4; r++) {
                float sv = s[j][r];
                if (masked) {
                    const int key = k0 + 32*(j & 1) + 8*quad + 4*(j >> 1) + r;
                    const float km = kpm[b*Sq + key] ? -1e30f : 0.0f;
                    sv += (am[(size_t)q*Sq + key] + km) * LOG2E;
                }
                p[r] = exp2f(sv);
            }
            lsum += (p[0]+p[1]) + (p[2]+p[3]);
            pk[j][0] = pkbf(p[0], p[1]);
            pk[j][1] = pkbf(p[2], p[3]);
        }

        // PV: O^T += V^T · P^T — P^T B-frag is lane-local by construction:
        // lane needs keys ks*32 + quad*8 + e  ==  {pk[ks], pk[ks+2]}
#pragma unroll
        for (int ks = 0; ks < 2; ks++) {
            union { int i[4]; bhalf8 v; } bp;
            bp.i[0] = pk[ks][0];
            bp.i[1] = pk[ks][1];
            bp.i[2] = pk[ks + 2][0];
            bp.i[3] = pk[ks + 2][1];
            bhalf8 av[4];
#pragma unroll
            for (int nd = 0; nd < 4; nd++)
                av[nd] = *(const bhalf8*)&Vs[ks*2048 + nd*512 + l*8];
#pragma unroll
            for (int nd = 0; nd < 4; nd++)
                o[nd] = __builtin_amdgcn_mfma_f32_16x16x32_bf16(av[nd], bp.v, o[nd], 0,0,0);
        }
    }

    lsum += __shfl_xor(lsum, 16, 64);
    lsum += __shfl_xor(lsum, 32, 64);
    const float rl = 1.0f / lsum;
    if (quad == 0) rlbuf[(size_t)bh*Sq + q] = rl * 0.0625f;   // pre-scaled by 1/H

#pragma unroll
    for (int nd = 0; nd < 4; nd++) {
        union { __hip_bfloat16 hx[4]; uint2 u; } ou;
#pragma unroll
        for (int r = 0; r < 4; r++) ou.hx[r] = __float2bfloat16(o[nd][r] * rl);
        *(uint2*)(wa + ((size_t)b*Sq + q)*Ee + h*Dd + nd*16 + quad*4) = ou.u;
    }
}

// ---------------- attn_mean: 128q x 64k, double-buffered K, prefetch-early ----------------
// 1024 blocks x 256 threads (4 waves); wave w owns q rows [q0 + w*32, +32).
// 1D grid XCD-pinned: blk&7 -> q0 low bits so the 32 kc-blocks sharing one Q
// slice run consecutively on one XCD. Per h (1 barrier): stage tile h+1 into
// Ks[(h+1)&1] (regs loaded an iteration earlier -> latency hidden under
// compute), issue loads for h+2, compute from Ks[h&1]. Q A-frags direct
// global; rlbuf is pre-scaled by 1/16.
__global__ __launch_bounds__(256) void attn_mean_k(
    const __hip_bfloat16* __restrict__ Qp, const __hip_bfloat16* __restrict__ Kp,
    const float* __restrict__ am, const unsigned char* __restrict__ kpm,
    const unsigned int* __restrict__ flag,
    const float* __restrict__ rlbuf, float* __restrict__ attn_mean)
{
    __shared__ __align__(16) __hip_bfloat16 Ks[2][4096];   // 2 x (64 keys x 64 d)
    const int t = threadIdx.x;
    const int w = t >> 6, l = t & 63, lm = l & 15, quad = l >> 4;
    const int blk = blockIdx.x;
    const int q0idx = (blk & 7) | (((blk >> 8) & 1) << 3);   // 0..15
    const int kc    = ((blk >> 3) & 31) * 64;
    const int b     = (blk >> 9) & 1;
    const int q0    = q0idx * 128;
    const bool masked = (flag[0] != 0u);

    const int g0 = swz(t), g1 = g0 + 256;
    const int off0 = tile_off(g0), off1 = tile_off(g1);
    const int qa = q0 + w*32;                 // wave's 32 q rows

    float macc[2][4][4] = {};
    uint4 kr0, kr1;

    // stage h=0 directly (no readers yet), issue loads for h=1
    {
        const __hip_bfloat16* kg = Kp + ((size_t)(b*Hh)*Sq + kc)*Dd;
        uint4 a0 = *(const uint4*)(kg + (size_t)g0*8);
        uint4 a1 = *(const uint4*)(kg + (size_t)g1*8);
        *(uint4*)&Ks[0][off0] = a0;
        *(uint4*)&Ks[0][off1] = a1;
        const __hip_bfloat16* kg1 = kg + (size_t)Sq*Dd;
        kr0 = *(const uint4*)(kg1 + (size_t)g0*8);
        kr1 = *(const uint4*)(kg1 + (size_t)g1*8);
    }

    for (int h = 0; h < Hh; h++) {
        __syncthreads();                      // Ks[h&1] visible; prev readers done
        if (h < Hh - 1) {                     // stage tile h+1 (regs already loaded)
            *(uint4*)&Ks[(h + 1) & 1][off0] = kr0;
            *(uint4*)&Ks[(h + 1) & 1][off1] = kr1;
            if (h < Hh - 2) {                 // issue loads for h+2 (hidden under compute)
                const __hip_bfloat16* kn = Kp + ((size_t)(b*Hh + h + 2)*Sq + kc)*Dd;
                kr0 = *(const uint4*)(kn + (size_t)g0*8);
                kr1 = *(const uint4*)(kn + (size_t)g1*8);
            }
        }

        const size_t base = (size_t)(b*Hh + h)*Sq;
        const __hip_bfloat16* Kc = Ks[h & 1];
#pragma unroll
        for (int su = 0; su < 2; su++) {
            const int qrow = qa + su*16;
            const __hip_bfloat16* qg = Qp + (base + qrow + lm)*Dd + quad*8;
            f32x4 s[4] = {};
#pragma unroll
            for (int f = 0; f < 2; f++) {
                bhalf8 aq = *(const bhalf8*)(qg + f*32);
#pragma unroll
                for (int j = 0; j < 4; j++) {
                    bhalf8 bk = *(const bhalf8*)&Kc[f*2048 + j*512 + l*8];
                    s[j] = __builtin_amdgcn_mfma_f32_16x16x32_bf16(aq, bk, s[j], 0,0,0);
                }
            }
            const f32x4 rl4 = *(const f32x4*)(rlbuf + base + qrow + quad*4);
#pragma unroll
            for (int j = 0; j < 4; j++)
#pragma unroll
                for (int r = 0; r < 4; r++) {
                    float sv = s[j][r];
                    if (masked) {
                        const int key = kc + j*16 + lm;
                        const float km = kpm[b*Sq + key] ? -1e30f : 0.0f;
                        sv += (am[(size_t)(qrow + quad*4 + r)*Sq + key] + km) * LOG2E;
                    }
                    macc[su][j][r] += exp2f(sv) * rl4[r];   // rl4 pre-scaled by 1/16
                }
        }
    }

#pragma unroll
    for (int su = 0; su < 2; su++)
#pragma unroll
        for (int j = 0; j < 4; j++)
#pragma unroll
            for (int r = 0; r < 4; r++)
                attn_mean[((size_t)b*Sq + qa + su*16 + quad*4 + r)*Sq + kc + j*16 + lm] =
                    macc[su][j][r];
}

// ---------------- GEMM 2: output projection, bf16 MFMA ----------------
__global__ __launch_bounds__(256) void gemm_out(
    const __hip_bfloat16* __restrict__ A, const __hip_bfloat16* __restrict__ Bw,
    const float* __restrict__ bias, float* __restrict__ outp)
{
    __shared__ __align__(16) __hip_bfloat16 As[128*32];
    __shared__ __align__(16) __hip_bfloat16 Bs[128*32];
    const int t = threadIdx.x;
    const int l = t & 63, lm = l & 15, quad = l >> 4;
    const int w = t >> 6;
    const int mw = (w & 1)*64, nw = (w >> 1)*64;
    const int m0 = blockIdx.y*128, n0 = blockIdx.x*128;

    const int srow = t >> 2;
    const int scol = (t & 3)*8;
    const __hip_bfloat16* ag = A  + (size_t)(m0 + srow)*1024 + scol;
    const __hip_bfloat16* bg = Bw + (size_t)(n0 + srow)*1024 + scol;
    __hip_bfloat16* al = As + t*8;
    __hip_bfloat16* bl = Bs + t*8;

    f32x4 acc[4][4] = {};
    for (int k0 = 0; k0 < 1024; k0 += 32) {
        __syncthreads();
        gld16(ag + k0, al);
        gld16(ag + (size_t)64*1024 + k0, al + 2048);
        gld16(bg + k0, bl);
        gld16(bg + (size_t)64*1024 + k0, bl + 2048);
        __syncthreads();
        bhalf8 af[4], bf[4];
#pragma unroll
        for (int i = 0; i < 4; i++) {
            af[i] = *(const bhalf8*)&As[(mw + i*16 + lm)*32 + quad*8];
            bf[i] = *(const bhalf8*)&Bs[(nw + i*16 + lm)*32 + quad*8];
        }
#pragma unroll
        for (int mf = 0; mf < 4; mf++)
#pragma unroll
            for (int nf = 0; nf < 4; nf++)
                acc[mf][nf] = __builtin_amdgcn_mfma_f32_16x16x32_bf16(af[mf], bf[nf], acc[mf][nf], 0,0,0);
    }
#pragma unroll
    for (int nf = 0; nf < 4; nf++) {
        const int n = n0 + nw + nf*16 + lm;
        const float bz = bias[n];
#pragma unroll
        for (int mf = 0; mf < 4; mf++)
#pragma unroll
            for (int r = 0; r < 4; r++) {
                const int m = m0 + mw + mf*16 + quad*4 + r;
                const int b2 = m >> 11, s2 = m & 2047;
                outp[((size_t)s2*Bb + b2)*Ee + n] = acc[mf][nf][r] + bz;
            }
    }
}

extern "C" void kernel_launch(void* const* d_in, const int* in_sizes, int n_in,
                              void* d_out, int out_size, void* d_ws, size_t ws_size,
                              hipStream_t stream) {
    const float*         x         = (const float*)d_in[0];
    const float*         attn_mask = (const float*)d_in[1];
    const unsigned char* kpm       = (const unsigned char*)d_in[2];
    const float*         qkv_w     = (const float*)d_in[3];
    const float*         qkv_b     = (const float*)d_in[4];
    const float*         out_w     = (const float*)d_in[5];
    const float*         out_b     = (const float*)d_in[6];

    float* outp      = (float*)d_out;
    float* attn_mean = outp + 4194304;          // S*B*E

    __hip_bfloat16* xb  = (__hip_bfloat16*)d_ws;     // 8 MB
    __hip_bfloat16* qwb = xb  + 4194304;             // 6 MB
    __hip_bfloat16* owb = qwb + 3145728;             // 2 MB
    __hip_bfloat16* Qp  = owb + 1048576;             // 8 MB (pre-scaled by QSCALE)
    __hip_bfloat16* Kp  = Qp  + 4194304;             // 8 MB
    __hip_bfloat16* Vt  = Kp  + 4194304;             // 8 MB (transposed [B,H,D,S])
    __hip_bfloat16* wab = Vt  + 4194304;             // 8 MB
    float* rlbuf        = (float*)(wab + 4194304);   // 256 KB (stores rl/16)
    unsigned int* flag  = (unsigned int*)(rlbuf + 65536);

    hipMemsetAsync(flag, 0, sizeof(unsigned int), stream);
    prep_k<<<12288, 256, 0, stream>>>(x, attn_mask, (const unsigned int*)kpm,
                                      qkv_w, out_w, xb, qwb, owb, flag);
    gemm_qkv<<<dim3(24, 32), 256, 0, stream>>>(xb, qwb, qkv_b, Qp, Kp, Vt);
    attn_mfma<<<dim3(1024), 256, 0, stream>>>(Qp, Kp, Vt, attn_mask, kpm, flag, wab, rlbuf);
    attn_mean_k<<<dim3(1024), 256, 0, stream>>>(Qp, Kp, attn_mask, kpm, flag, rlbuf, attn_mean);
    gemm_out<<<dim3(8, 32), 256, 0, stream>>>(wab, owb, out_b, outp);
}